// Round 7
// baseline (114.303 us; speedup 1.0000x reference)
//
#include <hip/hip_runtime.h>
#include <hip/hip_bf16.h>

#define HH 1024
#define LL 2048
#define BB 8
#define NN2 32     // complex modes
#define CT 128     // chunk size
#define NCH 16     // LL / CT

typedef short bf16x8 __attribute__((ext_vector_type(8)));
typedef float f32x4  __attribute__((ext_vector_type(4)));

static __device__ __forceinline__ unsigned short bfbits(float x) {
    __hip_bfloat16 h = __float2bfloat16(x);
    return *(unsigned short*)&h;
}
static __device__ __forceinline__ float f_from_bits(unsigned short b) {
    __hip_bfloat16 h; *(unsigned short*)&h = b; return __bfloat162float(h);
}
// exp(dA * p) for complex dA*p, native ops. dA.y >= 0, p >= 0.
static __device__ __forceinline__ float2 cexp_n(float2 dA, float p) {
    float mag = __expf(dA.x * p);
    float rev = dA.y * p * 0.15915494309f;
    rev -= floorf(rev);                       // [0,1) revolutions
    float ang = rev * 6.28318530718f;         // [0,2pi) -- safe for native sin/cos
    return make_float2(mag * __cosf(ang), mag * __sinf(ang));
}

// ---------------- ssm LDS pool offsets (bytes), 4-batch split version -------
#define S_U    0        // ushort U[64][128]    (16384) rows bc=bl*16+c
#define S_UN   16384    // union 16KB: AJ[64][128] -> K1/K2[128][64] -> AP[128][64]
#define S_P    32768    // ushort P/CS[64][64]  (8192)
#define S_KT   40960    // float kt[128]        (512)
#define S_DTA  41472    // float2 dtA[32]       (256)
#define S_CN   41728    // float2 Cn[32]        (256)
#define S_TOT  41984

#define SWZ(off, row) ((off) ^ (((row) & 7) << 4))

// ---------------------------------------------------------------------------
// Kernel 1: one block per (h, batch-half). 4 batches. MFMA chunked-scan SSM.
// 512 thr, 41KB LDS -> 3 blocks/CU.
// ---------------------------------------------------------------------------
__global__ __launch_bounds__(512, 6) void ssm_mfma(
    const float* __restrict__ u, const float* __restrict__ log_dt,
    const float* __restrict__ log_w_real, const float* __restrict__ w_imag,
    const float* __restrict__ C_re, const float* __restrict__ C_im,
    const float* __restrict__ Dp, __hip_bfloat16* __restrict__ g_out)
{
    extern __shared__ char smem[];
    float2* dtA = (float2*)(smem + S_DTA);
    float2* Cn  = (float2*)(smem + S_CN);
    float*  kt  = (float*)(smem + S_KT);

    const int tid  = threadIdx.x;
    const int lane = tid & 63;
    const int wave = tid >> 6;
    const int wm   = wave >> 2;     // 0..1 : 32 bc-rows each
    const int wn   = wave & 3;      // 0..3 : col groups
    const int h    = blockIdx.x;
    const int bh   = blockIdx.y;    // batch half: batches bh*4 .. bh*4+3

    // ---------------- ph0a: issue u loads; per-mode constants ---------------
    float4 ureg[4];
    #pragma unroll
    for (int q = 0; q < 4; ++q) {
        int b = bh * 4 + q;
        ureg[q] = *(const float4*)(u + ((size_t)(b * HH + h)) * LL + tid * 4);
    }
    if (tid < NN2) {
        int n = tid;
        float dt = expf(log_dt[h]);
        float wr = -expf(log_w_real[n]);
        float wi = w_imag[n];
        float dar = wr * dt, dai = wi * dt;
        dtA[n] = make_float2(dar, dai);
        float er = expf(dar);
        float sn, cs; sincosf(dai, &sn, &cs);   // accurate path, 1 wave only
        float exr = er * cs - 1.0f, exi = er * sn;
        float den = wr * wr + wi * wi;
        float fr = (exr * wr + exi * wi) / den;
        float fi = (exi * wr - exr * wi) / den;
        float cre = C_re[h * NN2 + n], cim = C_im[h * NN2 + n];
        Cn[n] = make_float2(cre * fr - cim * fi, cre * fi + cim * fr);
    }
    __syncthreads();

    // ---------------- ph0b: U bf16 write + AJ table + k-taps (native) -------
    #pragma unroll
    for (int q = 0; q < 4; ++q) {
        int row = q * 16 + (tid >> 5);          // bc row (4 local batches x 16 chunks)
        int j   = (tid & 31) * 4;
        ushort4 o;
        o.x = bfbits(ureg[q].x); o.y = bfbits(ureg[q].y);
        o.z = bfbits(ureg[q].z); o.w = bfbits(ureg[q].w);
        *(ushort4*)(smem + SWZ(S_U + row * 256 + j * 2, row)) = o;
    }
    // AJ rows 2n (re), 2n+1 (im); AJ[.][j] = a^(127-j)
    #pragma unroll
    for (int q = 0; q < 2; ++q) {
        int vidx = q * 512 + tid;               // 1024 tasks of 4 cols
        int n = vidx >> 5, j0 = (vidx & 31) * 4;
        float2 dA = dtA[n];
        float2 a0 = cexp_n(dA, (float)(127 - j0));
        float2 a1 = cexp_n(dA, (float)(126 - j0));
        float2 a2 = cexp_n(dA, (float)(125 - j0));
        float2 a3 = cexp_n(dA, (float)(124 - j0));
        ushort4 re, im;
        re.x = bfbits(a0.x); re.y = bfbits(a1.x); re.z = bfbits(a2.x); re.w = bfbits(a3.x);
        im.x = bfbits(a0.y); im.y = bfbits(a1.y); im.z = bfbits(a2.y); im.w = bfbits(a3.y);
        int r0 = 2 * n, r1 = 2 * n + 1;
        *(ushort4*)(smem + SWZ(S_UN + r0 * 256 + j0 * 2, r0)) = re;
        *(ushort4*)(smem + SWZ(S_UN + r1 * 256 + j0 * 2, r1)) = im;
    }
    {   // kt[t] = 2 Re sum_n Cn a^t : quad per tap, shfl reduce
        int t = tid >> 2, nb = (tid & 3) * 8;
        float s = 0.f;
        #pragma unroll
        for (int i = 0; i < 8; ++i) {
            int n = nb + i;
            float2 a = cexp_n(dtA[n], (float)t);
            float2 C = Cn[n];
            s += C.x * a.x - C.y * a.y;
        }
        s += __shfl_xor(s, 1);
        s += __shfl_xor(s, 2);
        if ((tid & 3) == 0) kt[t] = 2.0f * s;
    }
    __syncthreads();

    // ---------------- ph1: partials GEMM P[bc 64][n' 64] = U x AJ, K=128 ----
    f32x4 accP[2] = {};
    #pragma unroll
    for (int ks = 0; ks < 4; ++ks) {
        int kf = ks * 32 + (lane >> 4) * 8;
        bf16x8 a0, a1, b0;
        {
            int r = wm * 32 + (lane & 15);
            a0 = *(bf16x8*)(smem + SWZ(S_U + r * 256 + kf * 2, r));
            int r2 = r + 16;
            a1 = *(bf16x8*)(smem + SWZ(S_U + r2 * 256 + kf * 2, r2));
        }
        {
            int r = wn * 16 + (lane & 15);
            b0 = *(bf16x8*)(smem + SWZ(S_UN + r * 256 + kf * 2, r));
        }
        accP[0] = __builtin_amdgcn_mfma_f32_16x16x32_bf16(a0, b0, accP[0], 0, 0, 0);
        accP[1] = __builtin_amdgcn_mfma_f32_16x16x32_bf16(a1, b0, accP[1], 0, 0, 0);
    }
    // P store (own region; AJ reads already issued above, lgkm waits inserted)
    #pragma unroll
    for (int mt = 0; mt < 2; ++mt)
        #pragma unroll
        for (int r = 0; r < 4; ++r) {
            int row = wm * 32 + mt * 16 + (lane >> 4) * 4 + r;
            int col = wn * 16 + (lane & 15);
            *(unsigned short*)(smem + SWZ(S_P + row * 128 + col * 2, row)) =
                bfbits(accP[mt][r]);
        }
    __syncthreads();   // AJ reads + P stores complete

    // ---------------- ph2: K1 build (all) + scan (tid<128) ------------------
    #pragma unroll
    for (int q = 0; q < 16; ++q) {
        int idx = q * 512 + tid;                // 8192 entries
        int ttr = idx >> 6, j = idx & 63;
        float val = (ttr >= j) ? kt[ttr - j] : 0.0f;
        *(unsigned short*)(smem + SWZ(S_UN + ttr * 128 + j * 2, ttr)) = bfbits(val);
    }
    if (tid < 128) {
        int b = tid >> 5, n = tid & 31;         // local batch, mode
        float2 C = Cn[n];
        float2 A = cexp_n(dtA[n], 128.0f);      // a^128
        float sr = 0.f, si = 0.f;
        for (int c = 0; c < NCH; ++c) {
            int row = b * 16 + c;
            int off = SWZ(S_P + row * 128 + n * 4, row);
            unsigned int pv = *(unsigned int*)(smem + off);
            float pr = f_from_bits((unsigned short)(pv & 0xffff));
            float pi = f_from_bits((unsigned short)(pv >> 16));
            float csr = C.x * sr - C.y * si;
            float csi = C.x * si + C.y * sr;
            *(unsigned int*)(smem + off) =
                (unsigned)bfbits(csr) | ((unsigned)bfbits(csi) << 16);
            float nsr = A.x * sr - A.y * si + pr;
            float nsi = A.x * si + A.y * sr + pi;
            sr = nsr; si = nsi;
        }
    }
    __syncthreads();

    // ---------------- ph3a: conv GEMM half 1 (j in [0,64)) ------------------
    f32x4 acc[2][2] = {};
    #pragma unroll
    for (int ks = 0; ks < 2; ++ks) {
        int kf = ks * 32 + (lane >> 4) * 8;
        bf16x8 a0, a1, bv[2];
        {
            int r = wm * 32 + (lane & 15);
            a0 = *(bf16x8*)(smem + SWZ(S_U + r * 256 + kf * 2, r));
            int r2 = r + 16;
            a1 = *(bf16x8*)(smem + SWZ(S_U + r2 * 256 + kf * 2, r2));
        }
        #pragma unroll
        for (int nt = 0; nt < 2; ++nt) {
            int ttr = wn * 32 + nt * 16 + (lane & 15);
            bv[nt] = *(bf16x8*)(smem + SWZ(S_UN + ttr * 128 + kf * 2, ttr));
        }
        #pragma unroll
        for (int nt = 0; nt < 2; ++nt) {
            acc[0][nt] = __builtin_amdgcn_mfma_f32_16x16x32_bf16(a0, bv[nt], acc[0][nt], 0, 0, 0);
            acc[1][nt] = __builtin_amdgcn_mfma_f32_16x16x32_bf16(a1, bv[nt], acc[1][nt], 0, 0, 0);
        }
    }
    __syncthreads();   // K1 consumed

    // ---------------- ph3b: K2 build + conv GEMM half 2 ---------------------
    #pragma unroll
    for (int q = 0; q < 16; ++q) {
        int idx = q * 512 + tid;
        int ttr = idx >> 6, j = idx & 63;
        float val = (ttr >= 64 + j) ? kt[ttr - 64 - j] : 0.0f;
        *(unsigned short*)(smem + SWZ(S_UN + ttr * 128 + j * 2, ttr)) = bfbits(val);
    }
    __syncthreads();
    #pragma unroll
    for (int ks = 0; ks < 2; ++ks) {
        int kf = ks * 32 + (lane >> 4) * 8;
        bf16x8 a0, a1, bv[2];
        {
            int r = wm * 32 + (lane & 15);
            a0 = *(bf16x8*)(smem + SWZ(S_U + r * 256 + 128 + kf * 2, r));
            int r2 = r + 16;
            a1 = *(bf16x8*)(smem + SWZ(S_U + r2 * 256 + 128 + kf * 2, r2));
        }
        #pragma unroll
        for (int nt = 0; nt < 2; ++nt) {
            int ttr = wn * 32 + nt * 16 + (lane & 15);
            bv[nt] = *(bf16x8*)(smem + SWZ(S_UN + ttr * 128 + kf * 2, ttr));
        }
        #pragma unroll
        for (int nt = 0; nt < 2; ++nt) {
            acc[0][nt] = __builtin_amdgcn_mfma_f32_16x16x32_bf16(a0, bv[nt], acc[0][nt], 0, 0, 0);
            acc[1][nt] = __builtin_amdgcn_mfma_f32_16x16x32_bf16(a1, bv[nt], acc[1][nt], 0, 0, 0);
        }
    }
    __syncthreads();   // K2 consumed

    // ---------------- ph4: AP build + state GEMM ----------------------------
    // AP[tt][2n] = 2 Re a^(tt+1), AP[tt][2n+1] = -2 Im a^(tt+1)
    #pragma unroll
    for (int q = 0; q < 8; ++q) {
        int idx = q * 512 + tid;                // 4096 (n,tt) tasks
        int n = idx >> 7, ttr = idx & 127;
        float2 a = cexp_n(dtA[n], (float)(ttr + 1));
        int off = SWZ(S_UN + ttr * 128 + n * 4, ttr);
        *(unsigned int*)(smem + off) =
            (unsigned)bfbits(2.0f * a.x) | ((unsigned)bfbits(-2.0f * a.y) << 16);
    }
    __syncthreads();
    #pragma unroll
    for (int ks = 0; ks < 2; ++ks) {
        int kf = ks * 32 + (lane >> 4) * 8;
        bf16x8 a0, a1, bv[2];
        {
            int r = wm * 32 + (lane & 15);
            a0 = *(bf16x8*)(smem + SWZ(S_P + r * 128 + kf * 2, r));
            int r2 = r + 16;
            a1 = *(bf16x8*)(smem + SWZ(S_P + r2 * 128 + kf * 2, r2));
        }
        #pragma unroll
        for (int nt = 0; nt < 2; ++nt) {
            int ttr = wn * 32 + nt * 16 + (lane & 15);
            bv[nt] = *(bf16x8*)(smem + SWZ(S_UN + ttr * 128 + kf * 2, ttr));
        }
        #pragma unroll
        for (int nt = 0; nt < 2; ++nt) {
            acc[0][nt] = __builtin_amdgcn_mfma_f32_16x16x32_bf16(a0, bv[nt], acc[0][nt], 0, 0, 0);
            acc[1][nt] = __builtin_amdgcn_mfma_f32_16x16x32_bf16(a1, bv[nt], acc[1][nt], 0, 0, 0);
        }
    }

    // ---------------- ph5: epilogue: y = acc + D*u, GELU -> LDS -> stores ---
    const float Dv = Dp[h];
    #pragma unroll
    for (int mt = 0; mt < 2; ++mt)
        #pragma unroll
        for (int nt = 0; nt < 2; ++nt)
            #pragma unroll
            for (int r = 0; r < 4; ++r) {
                int row = wm * 32 + mt * 16 + (lane >> 4) * 4 + r;
                int ttr = wn * 32 + nt * 16 + (lane & 15);
                int off = SWZ(S_U + row * 256 + ttr * 2, row);
                float uv = f_from_bits(*(unsigned short*)(smem + off));
                float y = acc[mt][nt][r] + Dv * uv;
                float z = 0.7978845608f * (y + 0.044715f * y * y * y);
                float e = __expf(2.0f * z);
                float th = 1.0f - 2.0f / (e + 1.0f);
                float gel = 0.5f * y * (1.0f + th);
                *(unsigned short*)(smem + off) = bfbits(gel);   // owner-exclusive slot
            }
    __syncthreads();
    #pragma unroll
    for (int q = 0; q < 2; ++q) {
        int flat = q * 512 + tid;               // 1024 uint4 tiles
        int row = flat >> 4, c16 = flat & 15;
        uint4 v = *(uint4*)(smem + SWZ(S_U + row * 256 + c16 * 16, row));
        int b = bh * 4 + (row >> 4), c = row & 15;
        *(uint4*)(g_out + ((size_t)(b * HH + h)) * LL + c * CT + c16 * 8) = v;
    }
}

// ---------------------------------------------------------------------------
// Kernel 2: W (1024x1024 fp32) -> bf16
// ---------------------------------------------------------------------------
__global__ __launch_bounds__(256) void conv_w(
    const float* __restrict__ W, __hip_bfloat16* __restrict__ Wb)
{
    int i = blockIdx.x * 256 + threadIdx.x;
    float4 v = ((const float4*)W)[i];
    ushort4 o;
    o.x = bfbits(v.x); o.y = bfbits(v.y); o.z = bfbits(v.z); o.w = bfbits(v.w);
    ((ushort4*)Wb)[i] = o;
}

// ---------------------------------------------------------------------------
// Kernel 3: transpose g (B,H,L) bf16 -> gT (B,L,H) bf16
// ---------------------------------------------------------------------------
__global__ __launch_bounds__(256) void transpose_g(
    const __hip_bfloat16* __restrict__ g, __hip_bfloat16* __restrict__ gT)
{
    __shared__ __hip_bfloat16 t[64][66];
    const int tid = threadIdx.x;
    const int b  = blockIdx.z;
    const int h0 = blockIdx.x * 64;
    const int l0 = blockIdx.y * 64;

    #pragma unroll
    for (int q = 0; q < 2; ++q) {
        int idx = tid + q * 256;
        int r = idx >> 3, c8 = (idx & 7) * 8;
        uint4 v = *(const uint4*)(g + ((size_t)(b * HH + h0 + r)) * LL + l0 + c8);
        unsigned int* dst = (unsigned int*)&t[r][c8];
        dst[0] = v.x; dst[1] = v.y; dst[2] = v.z; dst[3] = v.w;
    }
    __syncthreads();
    #pragma unroll
    for (int q = 0; q < 2; ++q) {
        int idx = tid + q * 256;
        int r = idx >> 3, c8 = (idx & 7) * 8;
        unsigned short tmp[8];
        #pragma unroll
        for (int j = 0; j < 8; ++j) tmp[j] = *(unsigned short*)&t[c8 + j][r];
        uint4 o;
        o.x = (unsigned)tmp[0] | ((unsigned)tmp[1] << 16);
        o.y = (unsigned)tmp[2] | ((unsigned)tmp[3] << 16);
        o.z = (unsigned)tmp[4] | ((unsigned)tmp[5] << 16);
        o.w = (unsigned)tmp[6] | ((unsigned)tmp[7] << 16);
        *(uint4*)(gT + ((size_t)(b * LL + l0 + r)) * HH + h0 + c8) = o;
    }
}

// ---------------------------------------------------------------------------
// Kernel 4: out = Wb x gT^T + bias.  256x256 tile, BK=64, 8 waves, dbuf LDS,
// counted vmcnt (never 0 in loop), XOR-swizzled LDS, XCD-swizzled grid.
// ---------------------------------------------------------------------------
#define GSLOT 32768
#define STAGE_TILE(kt_, s_)                                                      \
    {                                                                            \
        const int k0_ = (kt_) * 64;                                              \
        _Pragma("unroll")                                                        \
        for (int v_ = 0; v_ < 4; ++v_) {                                         \
            int row_ = v_ * 64 + rsub;                                           \
            const __hip_bfloat16* ga_ = Wb + (size_t)(o0 + row_) * HH + k0_ + csw; \
            const __hip_bfloat16* gb_ = gT + (size_t)(n0 + row_) * HH + k0_ + csw; \
            char* dA_ = smem + (s_) * GSLOT + (v_ * 64 + wave * 8) * 128;        \
            char* dB_ = smem + 2 * GSLOT + (s_) * GSLOT + (v_ * 64 + wave * 8) * 128; \
            __builtin_amdgcn_global_load_lds(                                    \
                (const __attribute__((address_space(1))) void*)ga_,              \
                (__attribute__((address_space(3))) void*)dA_, 16, 0, 0);         \
            __builtin_amdgcn_global_load_lds(                                    \
                (const __attribute__((address_space(1))) void*)gb_,              \
                (__attribute__((address_space(3))) void*)dB_, 16, 0, 0);         \
        }                                                                        \
    }

#define COMPUTE_TILE(s_)                                                         \
    {                                                                            \
        const char* baseA = smem + (s_) * GSLOT;                                 \
        const char* baseB = smem + 2 * GSLOT + (s_) * GSLOT;                     \
        bf16x8 bfr[4][2];                                                        \
        _Pragma("unroll")                                                        \
        for (int nt = 0; nt < 4; ++nt)                                           \
            _Pragma("unroll")                                                    \
            for (int ks = 0; ks < 2; ++ks) {                                     \
                int rb = wn * 64 + nt * 16 + (lane & 15);                        \
                int c  = (ks * 32 + (lane >> 4) * 8) ^ ((rb & 7) << 3);          \
                bfr[nt][ks] = *(const bf16x8*)(baseB + rb * 128 + c * 2);        \
            }                                                                    \
        _Pragma("unroll")                                                        \
        for (int qq = 0; qq < 4; ++qq) {                                         \
            bf16x8 af[2][2];                                                     \
            _Pragma("unroll")                                                    \
            for (int mt = 0; mt < 2; ++mt)                                       \
                _Pragma("unroll")                                                \
                for (int ks = 0; ks < 2; ++ks) {                                 \
                    int ra = wm * 128 + (qq * 2 + mt) * 16 + (lane & 15);        \
                    int c  = (ks * 32 + (lane >> 4) * 8) ^ ((ra & 7) << 3);      \
                    af[mt][ks] = *(const bf16x8*)(baseA + ra * 128 + c * 2);     \
                }                                                                \
            __builtin_amdgcn_s_setprio(1);                                       \
            _Pragma("unroll")                                                    \
            for (int mt = 0; mt < 2; ++mt)                                       \
                _Pragma("unroll")                                                \
                for (int nt = 0; nt < 4; ++nt) {                                 \
                    acc[qq * 2 + mt][nt] = __builtin_amdgcn_mfma_f32_16x16x32_bf16( \
                        af[mt][0], bfr[nt][0], acc[qq * 2 + mt][nt], 0, 0, 0);   \
                    acc[qq * 2 + mt][nt] = __builtin_amdgcn_mfma_f32_16x16x32_bf16( \
                        af[mt][1], bfr[nt][1], acc[qq * 2 + mt][nt], 0, 0, 0);   \
                }                                                                \
            __builtin_amdgcn_s_setprio(0);                                       \
        }                                                                        \
    }

__global__ __launch_bounds__(512, 2) void out_gemm_256(
    const __hip_bfloat16* __restrict__ Wb,
    const __hip_bfloat16* __restrict__ gT,
    const float* __restrict__ bias,
    float* __restrict__ out)
{
    extern __shared__ char smem[];
    const int tid  = threadIdx.x;
    const int lane = tid & 63;
    const int wave = tid >> 6;
    const int wm = wave >> 2;
    const int wn = wave & 3;

    int wg  = blockIdx.x;
    int swz = (wg & 7) * 32 + (wg >> 3);
    const int o0 = (swz & 3) * 256;
    const int n0 = (swz >> 2) * 256;

    const int rsub = tid >> 3;
    const int csw  = ((tid & 7) ^ (rsub & 7)) << 3;

    f32x4 acc[8][4] = {};

    STAGE_TILE(0, 0)
    STAGE_TILE(1, 1)

    for (int t = 0; t < 15; ++t) {
        asm volatile("s_waitcnt vmcnt(8)" ::: "memory");
        __builtin_amdgcn_s_barrier();
        __builtin_amdgcn_sched_barrier(0);
        COMPUTE_TILE(t & 1)
        asm volatile("s_waitcnt lgkmcnt(0)" ::: "memory");
        __builtin_amdgcn_s_barrier();
        __builtin_amdgcn_sched_barrier(0);
        if (t < 14) STAGE_TILE(t + 2, t & 1)
    }
    asm volatile("s_waitcnt vmcnt(0)" ::: "memory");
    __builtin_amdgcn_s_barrier();
    __builtin_amdgcn_sched_barrier(0);
    COMPUTE_TILE(1)

    const int bb = n0 >> 11;
    #pragma unroll
    for (int m = 0; m < 8; ++m) {
        int o = o0 + wm * 128 + m * 16 + (lane >> 4) * 4;
        #pragma unroll
        for (int nt = 0; nt < 4; ++nt) {
            int n = n0 + wn * 64 + nt * 16 + (lane & 15);
            int l = n & 2047;
            #pragma unroll
            for (int r = 0; r < 4; ++r)
                out[((size_t)(bb * HH + o + r)) * LL + l] = acc[m][nt][r] + bias[o + r];
        }
    }
}

extern "C" void kernel_launch(void* const* d_in, const int* in_sizes, int n_in,
                              void* d_out, int out_size, void* d_ws, size_t ws_size,
                              hipStream_t stream) {
    const float* u          = (const float*)d_in[0];
    const float* log_dt     = (const float*)d_in[1];
    const float* log_w_real = (const float*)d_in[2];
    const float* w_imag     = (const float*)d_in[3];
    const float* C_re       = (const float*)d_in[4];
    const float* C_im       = (const float*)d_in[5];
    const float* Dp         = (const float*)d_in[6];
    const float* W          = (const float*)d_in[7];
    const float* bias       = (const float*)d_in[8];
    float* out = (float*)d_out;

    __hip_bfloat16* g  = (__hip_bfloat16*)d_out;                        // stash in d_out slack
    __hip_bfloat16* gT = (__hip_bfloat16*)d_ws;                         // 33.5 MB
    __hip_bfloat16* Wb = (__hip_bfloat16*)((char*)d_ws + 33554432);     // 2 MB

    hipFuncSetAttribute((const void*)ssm_mfma,
                        hipFuncAttributeMaxDynamicSharedMemorySize, S_TOT);
    hipFuncSetAttribute((const void*)out_gemm_256,
                        hipFuncAttributeMaxDynamicSharedMemorySize, 131072);

    conv_w<<<dim3(HH * HH / 1024), 256, 0, stream>>>(W, Wb);
    ssm_mfma<<<dim3(HH, 2), 512, S_TOT, stream>>>(u, log_dt, log_w_real, w_imag,
                                                  C_re, C_im, Dp, g);
    transpose_g<<<dim3(HH / 64, LL / 64, BB), 256, 0, stream>>>(g, gT);
    out_gemm_256<<<dim3(256), 512, 131072, stream>>>(Wb, gT, bias, out);
}

// Round 8
// 108.432 us; speedup vs baseline: 1.0541x; 1.0541x over previous
//
#include <hip/hip_runtime.h>
#include <hip/hip_bf16.h>

#define HH 1024
#define LL 2048
#define BB 8
#define NN2 32     // complex modes
#define CT 128     // chunk size
#define NCH 16     // LL / CT

typedef short bf16x8 __attribute__((ext_vector_type(8)));
typedef float f32x4  __attribute__((ext_vector_type(4)));

static __device__ __forceinline__ unsigned short bfbits(float x) {
    __hip_bfloat16 h = __float2bfloat16(x);
    return *(unsigned short*)&h;
}
static __device__ __forceinline__ float f_from_bits(unsigned short b) {
    __hip_bfloat16 h; *(unsigned short*)&h = b; return __bfloat162float(h);
}
// exp(dA * p), native ops, explicit range reduction.
static __device__ __forceinline__ float2 cexp_n(float2 dA, float p) {
    float mag = __expf(dA.x * p);
    float rev = dA.y * p * 0.15915494309f;
    rev -= floorf(rev);
    float ang = rev * 6.28318530718f;
    return make_float2(mag * __cosf(ang), mag * __sinf(ang));
}

#define SWZ(off, row) ((off) ^ (((row) & 7) << 4))

// ---------------------------------------------------------------------------
// Kernel 0: per-h tables -> global, PRE-SWIZZLED for global_load_lds staging.
// AJ_g[h]: 16KB  rows 2n/2n+1 (re/im), AJ[.][j] = a^(127-j)   (64x128 bf16)
// AP_g[h]: 16KB  AP[tt][2n]=2Re a^(tt+1), [2n+1]=-2Im         (128x64 bf16)
// misc_g[h]: 256 floats = kt[128] | Cn interleaved[64] | a^128 interleaved[64]
// ---------------------------------------------------------------------------
__global__ __launch_bounds__(256) void aux_tables(
    const float* __restrict__ log_dt, const float* __restrict__ log_w_real,
    const float* __restrict__ w_imag, const float* __restrict__ C_re,
    const float* __restrict__ C_im,
    __hip_bfloat16* __restrict__ AJ_g, __hip_bfloat16* __restrict__ AP_g,
    float* __restrict__ misc_g)
{
    __shared__ float2 dtA_s[NN2];
    __shared__ float2 Cn_s[NN2];
    const int tid = threadIdx.x;
    const int h = blockIdx.x;

    if (tid < NN2) {
        int n = tid;
        float dt = expf(log_dt[h]);
        float wr = -expf(log_w_real[n]);
        float wi = w_imag[n];
        float dar = wr * dt, dai = wi * dt;
        dtA_s[n] = make_float2(dar, dai);
        float er = expf(dar);
        float sn, cs; sincosf(dai, &sn, &cs);
        float exr = er * cs - 1.0f, exi = er * sn;
        float den = wr * wr + wi * wi;
        float fr = (exr * wr + exi * wi) / den;
        float fi = (exi * wr - exr * wi) / den;
        float cre = C_re[h * NN2 + n], cim = C_im[h * NN2 + n];
        float2 Cv = make_float2(cre * fr - cim * fi, cre * fi + cim * fr);
        Cn_s[n] = Cv;
        misc_g[h * 256 + 128 + 2 * n]     = Cv.x;
        misc_g[h * 256 + 128 + 2 * n + 1] = Cv.y;
        float magA = expf(dar * 128.0f);
        float snA, csA; sincosf(dai * 128.0f, &snA, &csA);
        misc_g[h * 256 + 192 + 2 * n]     = magA * csA;
        misc_g[h * 256 + 192 + 2 * n + 1] = magA * snA;
    }
    __syncthreads();

    char* ajb = (char*)AJ_g + (size_t)h * 16384;
    #pragma unroll
    for (int q = 0; q < 2; ++q) {
        int task = q * 256 + tid;              // 512 tasks: (n, j0 block of 8)
        int n = task >> 4, j0 = (task & 15) * 8;
        float2 dA = dtA_s[n];
        unsigned rw[4], iw[4];
        #pragma unroll
        for (int i2 = 0; i2 < 4; ++i2) {
            float2 a0 = cexp_n(dA, (float)(127 - j0 - 2 * i2));
            float2 a1 = cexp_n(dA, (float)(127 - j0 - 2 * i2 - 1));
            rw[i2] = (unsigned)bfbits(a0.x) | ((unsigned)bfbits(a1.x) << 16);
            iw[i2] = (unsigned)bfbits(a0.y) | ((unsigned)bfbits(a1.y) << 16);
        }
        int r0 = 2 * n, r1 = 2 * n + 1;
        *(uint4*)(ajb + SWZ(r0 * 256 + j0 * 2, r0)) = make_uint4(rw[0], rw[1], rw[2], rw[3]);
        *(uint4*)(ajb + SWZ(r1 * 256 + j0 * 2, r1)) = make_uint4(iw[0], iw[1], iw[2], iw[3]);
    }

    char* apb = (char*)AP_g + (size_t)h * 16384;
    #pragma unroll
    for (int q = 0; q < 2; ++q) {
        int task = q * 256 + tid;              // 512 tasks: (ttr, n0 block of 8)
        int ttr = task >> 2, n0 = (task & 3) * 8;
        unsigned w[8];
        #pragma unroll
        for (int i = 0; i < 8; ++i) {
            float2 a = cexp_n(dtA_s[n0 + i], (float)(ttr + 1));
            w[i] = (unsigned)bfbits(2.0f * a.x) | ((unsigned)bfbits(-2.0f * a.y) << 16);
        }
        *(uint4*)(apb + SWZ(ttr * 128 + n0 * 4, ttr))      = make_uint4(w[0], w[1], w[2], w[3]);
        *(uint4*)(apb + SWZ(ttr * 128 + n0 * 4 + 16, ttr)) = make_uint4(w[4], w[5], w[6], w[7]);
    }

    {   // kt[t] = 2 Re sum_n Cn a^t : 2 threads per tap
        int t = tid >> 1, nb = (tid & 1) * 16;
        float s = 0.f;
        #pragma unroll
        for (int i = 0; i < 16; ++i) {
            int n = nb + i;
            float2 a = cexp_n(dtA_s[n], (float)t);
            float2 C = Cn_s[n];
            s += C.x * a.x - C.y * a.y;
        }
        s += __shfl_xor(s, 1);
        if ((tid & 1) == 0) misc_g[h * 256 + t] = 2.0f * s;
    }
}

// ---------------- ssm LDS pool offsets (bytes) ----------------
#define S_U    0        // ushort U[64][128] swz (16384)
#define S_UN   16384    // 16KB union: AJ -> K1/K2[128][64] -> AP[128][64]
#define S_P    32768    // ushort P/CS[64][64] swz (8192)
#define S_KT   40960    // kt[128] f32 | Cn f2[32] | A128 f2[32]  (1024)
#define S_TOT  41984

// K build from kt: K[ttr][j] = kt[ttr - hf*64 - j] (or 0)
#define KBUILD(hf)                                                       \
    _Pragma("unroll")                                                    \
    for (int q = 0; q < 4; ++q) {                                        \
        int idx = q * 512 + tid;                                         \
        int ttr = idx >> 4, j0 = (idx & 15) * 4;                         \
        int base = ttr - (hf) * 64 - j0;                                 \
        ushort4 o;                                                       \
        o.x = (base     >= 0) ? bfbits(kt[base])     : (unsigned short)0;\
        o.y = (base - 1 >= 0) ? bfbits(kt[base - 1]) : (unsigned short)0;\
        o.z = (base - 2 >= 0) ? bfbits(kt[base - 2]) : (unsigned short)0;\
        o.w = (base - 3 >= 0) ? bfbits(kt[base - 3]) : (unsigned short)0;\
        *(ushort4*)(smem + SWZ(S_UN + ttr * 128 + j0 * 2, ttr)) = o;     \
    }

// ---------------------------------------------------------------------------
// Kernel 1: one block per (h, batch-half). Tables staged from global.
// ---------------------------------------------------------------------------
__global__ __launch_bounds__(512, 6) void ssm_mfma(
    const float* __restrict__ u,
    const __hip_bfloat16* __restrict__ AJ_g,
    const __hip_bfloat16* __restrict__ AP_g,
    const float* __restrict__ misc_g,
    const float* __restrict__ Dp, __hip_bfloat16* __restrict__ g_out)
{
    extern __shared__ char smem[];
    float*  kt   = (float*)(smem + S_KT);
    float2* CnL  = (float2*)(smem + S_KT + 512);
    float2* A128 = (float2*)(smem + S_KT + 768);

    const int tid  = threadIdx.x;
    const int lane = tid & 63;
    const int wave = tid >> 6;
    const int wm   = wave >> 2;     // 0..1 : 32 bc-rows each
    const int wn   = wave & 3;      // 0..3 : col groups
    const int h    = blockIdx.x;
    const int bh   = blockIdx.y;

    // ---- issue table staging (AJ 16KB -> S_UN, misc 1KB -> S_KT) ----------
    {
        const char* ajs = (const char*)AJ_g + (size_t)h * 16384;
        __builtin_amdgcn_global_load_lds(
            (const __attribute__((address_space(1))) void*)(ajs + tid * 16),
            (__attribute__((address_space(3))) void*)(smem + S_UN + wave * 1024), 16, 0, 0);
        __builtin_amdgcn_global_load_lds(
            (const __attribute__((address_space(1))) void*)(ajs + 8192 + tid * 16),
            (__attribute__((address_space(3))) void*)(smem + S_UN + 8192 + wave * 1024), 16, 0, 0);
        if (tid < 64) {
            const char* ms = (const char*)misc_g + (size_t)h * 1024;
            __builtin_amdgcn_global_load_lds(
                (const __attribute__((address_space(1))) void*)(ms + tid * 16),
                (__attribute__((address_space(3))) void*)(smem + S_KT), 16, 0, 0);
        }
    }

    // ---- u load + bf16 convert -> U LDS ------------------------------------
    float4 ureg[4];
    #pragma unroll
    for (int q = 0; q < 4; ++q) {
        int b = bh * 4 + q;
        ureg[q] = *(const float4*)(u + ((size_t)(b * HH + h)) * LL + tid * 4);
    }
    #pragma unroll
    for (int q = 0; q < 4; ++q) {
        int row = q * 16 + (tid >> 5);
        int j   = (tid & 31) * 4;
        ushort4 o;
        o.x = bfbits(ureg[q].x); o.y = bfbits(ureg[q].y);
        o.z = bfbits(ureg[q].z); o.w = bfbits(ureg[q].w);
        *(ushort4*)(smem + SWZ(S_U + row * 256 + j * 2, row)) = o;
    }
    asm volatile("s_waitcnt vmcnt(0)" ::: "memory");
    __syncthreads();                                         // [1] AJ/misc/U ready

    // ---- ph1: partials GEMM P[bc 64][n' 64] = U x AJ, K=128 ---------------
    f32x4 accP[2] = {};
    #pragma unroll
    for (int ks = 0; ks < 4; ++ks) {
        int kf = ks * 32 + (lane >> 4) * 8;
        bf16x8 a0, a1, b0;
        {
            int r = wm * 32 + (lane & 15);
            a0 = *(bf16x8*)(smem + SWZ(S_U + r * 256 + kf * 2, r));
            int r2 = r + 16;
            a1 = *(bf16x8*)(smem + SWZ(S_U + r2 * 256 + kf * 2, r2));
        }
        {
            int r = wn * 16 + (lane & 15);
            b0 = *(bf16x8*)(smem + SWZ(S_UN + r * 256 + kf * 2, r));
        }
        accP[0] = __builtin_amdgcn_mfma_f32_16x16x32_bf16(a0, b0, accP[0], 0, 0, 0);
        accP[1] = __builtin_amdgcn_mfma_f32_16x16x32_bf16(a1, b0, accP[1], 0, 0, 0);
    }
    #pragma unroll
    for (int mt = 0; mt < 2; ++mt)
        #pragma unroll
        for (int r = 0; r < 4; ++r) {
            int row = wm * 32 + mt * 16 + (lane >> 4) * 4 + r;
            int col = wn * 16 + (lane & 15);
            *(unsigned short*)(smem + SWZ(S_P + row * 128 + col * 2, row)) =
                bfbits(accP[mt][r]);
        }
    __syncthreads();                                         // [2] AJ consumed, P ready

    // ---- ph2: K1 build + scan ---------------------------------------------
    KBUILD(0)
    if (tid < 128) {
        int b = tid >> 5, n = tid & 31;
        float2 C = CnL[n];
        float2 A = A128[n];
        float sr = 0.f, si = 0.f;
        for (int c = 0; c < NCH; ++c) {
            int row = b * 16 + c;
            int off = SWZ(S_P + row * 128 + n * 4, row);
            unsigned int pv = *(unsigned int*)(smem + off);
            float pr = f_from_bits((unsigned short)(pv & 0xffff));
            float pi = f_from_bits((unsigned short)(pv >> 16));
            float csr = C.x * sr - C.y * si;
            float csi = C.x * si + C.y * sr;
            *(unsigned int*)(smem + off) =
                (unsigned)bfbits(csr) | ((unsigned)bfbits(csi) << 16);
            float nsr = A.x * sr - A.y * si + pr;
            float nsi = A.x * si + A.y * sr + pi;
            sr = nsr; si = nsi;
        }
    }
    __syncthreads();                                         // [3] K1/CS ready

    // ---- ph3a: conv GEMM half 1 -------------------------------------------
    f32x4 acc[2][2] = {};
    #pragma unroll
    for (int ks = 0; ks < 2; ++ks) {
        int kf = ks * 32 + (lane >> 4) * 8;
        bf16x8 a0, a1, bv[2];
        {
            int r = wm * 32 + (lane & 15);
            a0 = *(bf16x8*)(smem + SWZ(S_U + r * 256 + kf * 2, r));
            int r2 = r + 16;
            a1 = *(bf16x8*)(smem + SWZ(S_U + r2 * 256 + kf * 2, r2));
        }
        #pragma unroll
        for (int nt = 0; nt < 2; ++nt) {
            int ttr = wn * 32 + nt * 16 + (lane & 15);
            bv[nt] = *(bf16x8*)(smem + SWZ(S_UN + ttr * 128 + kf * 2, ttr));
        }
        #pragma unroll
        for (int nt = 0; nt < 2; ++nt) {
            acc[0][nt] = __builtin_amdgcn_mfma_f32_16x16x32_bf16(a0, bv[nt], acc[0][nt], 0, 0, 0);
            acc[1][nt] = __builtin_amdgcn_mfma_f32_16x16x32_bf16(a1, bv[nt], acc[1][nt], 0, 0, 0);
        }
    }
    __syncthreads();                                         // [4] K1 consumed

    // ---- ph3b: K2 build + conv GEMM half 2 --------------------------------
    KBUILD(1)
    __syncthreads();                                         // [5] K2 ready
    #pragma unroll
    for (int ks = 0; ks < 2; ++ks) {
        int kf = ks * 32 + (lane >> 4) * 8;
        bf16x8 a0, a1, bv[2];
        {
            int r = wm * 32 + (lane & 15);
            a0 = *(bf16x8*)(smem + SWZ(S_U + r * 256 + 128 + kf * 2, r));
            int r2 = r + 16;
            a1 = *(bf16x8*)(smem + SWZ(S_U + r2 * 256 + 128 + kf * 2, r2));
        }
        #pragma unroll
        for (int nt = 0; nt < 2; ++nt) {
            int ttr = wn * 32 + nt * 16 + (lane & 15);
            bv[nt] = *(bf16x8*)(smem + SWZ(S_UN + ttr * 128 + kf * 2, ttr));
        }
        #pragma unroll
        for (int nt = 0; nt < 2; ++nt) {
            acc[0][nt] = __builtin_amdgcn_mfma_f32_16x16x32_bf16(a0, bv[nt], acc[0][nt], 0, 0, 0);
            acc[1][nt] = __builtin_amdgcn_mfma_f32_16x16x32_bf16(a1, bv[nt], acc[1][nt], 0, 0, 0);
        }
    }
    __syncthreads();                                         // [6] K2 consumed, UN free

    // ---- stage AP -> S_UN, then state GEMM --------------------------------
    {
        const char* aps = (const char*)AP_g + (size_t)h * 16384;
        __builtin_amdgcn_global_load_lds(
            (const __attribute__((address_space(1))) void*)(aps + tid * 16),
            (__attribute__((address_space(3))) void*)(smem + S_UN + wave * 1024), 16, 0, 0);
        __builtin_amdgcn_global_load_lds(
            (const __attribute__((address_space(1))) void*)(aps + 8192 + tid * 16),
            (__attribute__((address_space(3))) void*)(smem + S_UN + 8192 + wave * 1024), 16, 0, 0);
    }
    asm volatile("s_waitcnt vmcnt(0)" ::: "memory");
    __syncthreads();                                         // [7] AP ready

    #pragma unroll
    for (int ks = 0; ks < 2; ++ks) {
        int kf = ks * 32 + (lane >> 4) * 8;
        bf16x8 a0, a1, bv[2];
        {
            int r = wm * 32 + (lane & 15);
            a0 = *(bf16x8*)(smem + SWZ(S_P + r * 128 + kf * 2, r));
            int r2 = r + 16;
            a1 = *(bf16x8*)(smem + SWZ(S_P + r2 * 128 + kf * 2, r2));
        }
        #pragma unroll
        for (int nt = 0; nt < 2; ++nt) {
            int ttr = wn * 32 + nt * 16 + (lane & 15);
            bv[nt] = *(bf16x8*)(smem + SWZ(S_UN + ttr * 128 + kf * 2, ttr));
        }
        #pragma unroll
        for (int nt = 0; nt < 2; ++nt) {
            acc[0][nt] = __builtin_amdgcn_mfma_f32_16x16x32_bf16(a0, bv[nt], acc[0][nt], 0, 0, 0);
            acc[1][nt] = __builtin_amdgcn_mfma_f32_16x16x32_bf16(a1, bv[nt], acc[1][nt], 0, 0, 0);
        }
    }

    // ---- epilogue: y = acc + D*u, GELU -> LDS -> packed stores ------------
    const float Dv = Dp[h];
    #pragma unroll
    for (int mt = 0; mt < 2; ++mt)
        #pragma unroll
        for (int nt = 0; nt < 2; ++nt)
            #pragma unroll
            for (int r = 0; r < 4; ++r) {
                int row = wm * 32 + mt * 16 + (lane >> 4) * 4 + r;
                int ttr = wn * 32 + nt * 16 + (lane & 15);
                int off = SWZ(S_U + row * 256 + ttr * 2, row);
                float uv = f_from_bits(*(unsigned short*)(smem + off));
                float y = acc[mt][nt][r] + Dv * uv;
                float z = 0.7978845608f * (y + 0.044715f * y * y * y);
                float e = __expf(2.0f * z);
                float th = 1.0f - 2.0f / (e + 1.0f);
                float gel = 0.5f * y * (1.0f + th);
                *(unsigned short*)(smem + off) = bfbits(gel);
            }
    __syncthreads();                                         // [8]
    #pragma unroll
    for (int q = 0; q < 2; ++q) {
        int flat = q * 512 + tid;
        int row = flat >> 4, c16 = flat & 15;
        uint4 v = *(uint4*)(smem + SWZ(S_U + row * 256 + c16 * 16, row));
        int b = bh * 4 + (row >> 4), c = row & 15;
        *(uint4*)(g_out + ((size_t)(b * HH + h)) * LL + c * CT + c16 * 8) = v;
    }
}

// ---------------------------------------------------------------------------
// Kernel 2: W (1024x1024 fp32) -> bf16
// ---------------------------------------------------------------------------
__global__ __launch_bounds__(256) void conv_w(
    const float* __restrict__ W, __hip_bfloat16* __restrict__ Wb)
{
    int i = blockIdx.x * 256 + threadIdx.x;
    float4 v = ((const float4*)W)[i];
    ushort4 o;
    o.x = bfbits(v.x); o.y = bfbits(v.y); o.z = bfbits(v.z); o.w = bfbits(v.w);
    ((ushort4*)Wb)[i] = o;
}

// ---------------------------------------------------------------------------
// Kernel 3: transpose g (B,H,L) bf16 -> gT (B,L,H) bf16
// ---------------------------------------------------------------------------
__global__ __launch_bounds__(256) void transpose_g(
    const __hip_bfloat16* __restrict__ g, __hip_bfloat16* __restrict__ gT)
{
    __shared__ __hip_bfloat16 t[64][66];
    const int tid = threadIdx.x;
    const int b  = blockIdx.z;
    const int h0 = blockIdx.x * 64;
    const int l0 = blockIdx.y * 64;

    #pragma unroll
    for (int q = 0; q < 2; ++q) {
        int idx = tid + q * 256;
        int r = idx >> 3, c8 = (idx & 7) * 8;
        uint4 v = *(const uint4*)(g + ((size_t)(b * HH + h0 + r)) * LL + l0 + c8);
        unsigned int* dst = (unsigned int*)&t[r][c8];
        dst[0] = v.x; dst[1] = v.y; dst[2] = v.z; dst[3] = v.w;
    }
    __syncthreads();
    #pragma unroll
    for (int q = 0; q < 2; ++q) {
        int idx = tid + q * 256;
        int r = idx >> 3, c8 = (idx & 7) * 8;
        unsigned short tmp[8];
        #pragma unroll
        for (int j = 0; j < 8; ++j) tmp[j] = *(unsigned short*)&t[c8 + j][r];
        uint4 o;
        o.x = (unsigned)tmp[0] | ((unsigned)tmp[1] << 16);
        o.y = (unsigned)tmp[2] | ((unsigned)tmp[3] << 16);
        o.z = (unsigned)tmp[4] | ((unsigned)tmp[5] << 16);
        o.w = (unsigned)tmp[6] | ((unsigned)tmp[7] << 16);
        *(uint4*)(gT + ((size_t)(b * LL + l0 + r)) * HH + h0 + c8) = o;
    }
}

// ---------------------------------------------------------------------------
// Kernel 4: out = Wb x gT^T + bias (unchanged from R7)
// ---------------------------------------------------------------------------
#define GSLOT 32768
#define STAGE_TILE(kt_, s_)                                                      \
    {                                                                            \
        const int k0_ = (kt_) * 64;                                              \
        _Pragma("unroll")                                                        \
        for (int v_ = 0; v_ < 4; ++v_) {                                         \
            int row_ = v_ * 64 + rsub;                                           \
            const __hip_bfloat16* ga_ = Wb + (size_t)(o0 + row_) * HH + k0_ + csw; \
            const __hip_bfloat16* gb_ = gT + (size_t)(n0 + row_) * HH + k0_ + csw; \
            char* dA_ = smem + (s_) * GSLOT + (v_ * 64 + wave * 8) * 128;        \
            char* dB_ = smem + 2 * GSLOT + (s_) * GSLOT + (v_ * 64 + wave * 8) * 128; \
            __builtin_amdgcn_global_load_lds(                                    \
                (const __attribute__((address_space(1))) void*)ga_,              \
                (__attribute__((address_space(3))) void*)dA_, 16, 0, 0);         \
            __builtin_amdgcn_global_load_lds(                                    \
                (const __attribute__((address_space(1))) void*)gb_,              \
                (__attribute__((address_space(3))) void*)dB_, 16, 0, 0);         \
        }                                                                        \
    }

#define COMPUTE_TILE(s_)                                                         \
    {                                                                            \
        const char* baseA = smem + (s_) * GSLOT;                                 \
        const char* baseB = smem + 2 * GSLOT + (s_) * GSLOT;                     \
        bf16x8 bfr[4][2];                                                        \
        _Pragma("unroll")                                                        \
        for (int nt = 0; nt < 4; ++nt)                                           \
            _Pragma("unroll")                                                    \
            for (int ks = 0; ks < 2; ++ks) {                                     \
                int rb = wn * 64 + nt * 16 + (lane & 15);                        \
                int c  = (ks * 32 + (lane >> 4) * 8) ^ ((rb & 7) << 3);          \
                bfr[nt][ks] = *(const bf16x8*)(baseB + rb * 128 + c * 2);        \
            }                                                                    \
        _Pragma("unroll")                                                        \
        for (int qq = 0; qq < 4; ++qq) {                                         \
            bf16x8 af[2][2];                                                     \
            _Pragma("unroll")                                                    \
            for (int mt = 0; mt < 2; ++mt)                                       \
                _Pragma("unroll")                                                \
                for (int ks = 0; ks < 2; ++ks) {                                 \
                    int ra = wm * 128 + (qq * 2 + mt) * 16 + (lane & 15);        \
                    int c  = (ks * 32 + (lane >> 4) * 8) ^ ((ra & 7) << 3);      \
                    af[mt][ks] = *(const bf16x8*)(baseA + ra * 128 + c * 2);     \
                }                                                                \
            __builtin_amdgcn_s_setprio(1);                                       \
            _Pragma("unroll")                                                    \
            for (int mt = 0; mt < 2; ++mt)                                       \
                _Pragma("unroll")                                                \
                for (int nt = 0; nt < 4; ++nt) {                                 \
                    acc[qq * 2 + mt][nt] = __builtin_amdgcn_mfma_f32_16x16x32_bf16( \
                        af[mt][0], bfr[nt][0], acc[qq * 2 + mt][nt], 0, 0, 0);   \
                    acc[qq * 2 + mt][nt] = __builtin_amdgcn_mfma_f32_16x16x32_bf16( \
                        af[mt][1], bfr[nt][1], acc[qq * 2 + mt][nt], 0, 0, 0);   \
                }                                                                \
            __builtin_amdgcn_s_setprio(0);                                       \
        }                                                                        \
    }

__global__ __launch_bounds__(512, 2) void out_gemm_256(
    const __hip_bfloat16* __restrict__ Wb,
    const __hip_bfloat16* __restrict__ gT,
    const float* __restrict__ bias,
    float* __restrict__ out)
{
    extern __shared__ char smem[];
    const int tid  = threadIdx.x;
    const int lane = tid & 63;
    const int wave = tid >> 6;
    const int wm = wave >> 2;
    const int wn = wave & 3;

    int wg  = blockIdx.x;
    int swz = (wg & 7) * 32 + (wg >> 3);
    const int o0 = (swz & 3) * 256;
    const int n0 = (swz >> 2) * 256;

    const int rsub = tid >> 3;
    const int csw  = ((tid & 7) ^ (rsub & 7)) << 3;

    f32x4 acc[8][4] = {};

    STAGE_TILE(0, 0)
    STAGE_TILE(1, 1)

    for (int t = 0; t < 15; ++t) {
        asm volatile("s_waitcnt vmcnt(8)" ::: "memory");
        __builtin_amdgcn_s_barrier();
        __builtin_amdgcn_sched_barrier(0);
        COMPUTE_TILE(t & 1)
        asm volatile("s_waitcnt lgkmcnt(0)" ::: "memory");
        __builtin_amdgcn_s_barrier();
        __builtin_amdgcn_sched_barrier(0);
        if (t < 14) STAGE_TILE(t + 2, t & 1)
    }
    asm volatile("s_waitcnt vmcnt(0)" ::: "memory");
    __builtin_amdgcn_s_barrier();
    __builtin_amdgcn_sched_barrier(0);
    COMPUTE_TILE(1)

    const int bb = n0 >> 11;
    #pragma unroll
    for (int m = 0; m < 8; ++m) {
        int o = o0 + wm * 128 + m * 16 + (lane >> 4) * 4;
        #pragma unroll
        for (int nt = 0; nt < 4; ++nt) {
            int n = n0 + wn * 64 + nt * 16 + (lane & 15);
            int l = n & 2047;
            #pragma unroll
            for (int r = 0; r < 4; ++r)
                out[((size_t)(bb * HH + o + r)) * LL + l] = acc[m][nt][r] + bias[o + r];
        }
    }
}

extern "C" void kernel_launch(void* const* d_in, const int* in_sizes, int n_in,
                              void* d_out, int out_size, void* d_ws, size_t ws_size,
                              hipStream_t stream) {
    const float* u          = (const float*)d_in[0];
    const float* log_dt     = (const float*)d_in[1];
    const float* log_w_real = (const float*)d_in[2];
    const float* w_imag     = (const float*)d_in[3];
    const float* C_re       = (const float*)d_in[4];
    const float* C_im       = (const float*)d_in[5];
    const float* Dp         = (const float*)d_in[6];
    const float* W          = (const float*)d_in[7];
    const float* bias       = (const float*)d_in[8];
    float* out = (float*)d_out;

    // d_out (64 MiB) = [AJ 16 MiB][AP 16 MiB][g 32 MiB]  (all consumed before
    // the final GEMM overwrites every byte of d_out)
    __hip_bfloat16* AJ_g = (__hip_bfloat16*)d_out;
    __hip_bfloat16* AP_g = (__hip_bfloat16*)((char*)d_out + 16777216);
    __hip_bfloat16* g    = (__hip_bfloat16*)((char*)d_out + 33554432);
    // ws: gT 33.5MB | Wb 2MB | misc 1MB
    __hip_bfloat16* gT     = (__hip_bfloat16*)d_ws;
    __hip_bfloat16* Wb     = (__hip_bfloat16*)((char*)d_ws + 33554432);
    float*          misc_g = (float*)((char*)d_ws + 35651584);

    hipFuncSetAttribute((const void*)ssm_mfma,
                        hipFuncAttributeMaxDynamicSharedMemorySize, S_TOT);
    hipFuncSetAttribute((const void*)out_gemm_256,
                        hipFuncAttributeMaxDynamicSharedMemorySize, 131072);

    conv_w<<<dim3(HH * HH / 1024), 256, 0, stream>>>(W, Wb);
    aux_tables<<<dim3(HH), 256, 0, stream>>>(log_dt, log_w_real, w_imag,
                                             C_re, C_im, AJ_g, AP_g, misc_g);
    ssm_mfma<<<dim3(HH, 2), 512, S_TOT, stream>>>(u, AJ_g, AP_g, misc_g, Dp, g);
    transpose_g<<<dim3(HH / 64, LL / 64, BB), 256, 0, stream>>>(g, gT);
    out_gemm_256<<<dim3(256), 512, 131072, stream>>>(Wb, gT, bias, out);
}

// Round 9
// 107.568 us; speedup vs baseline: 1.0626x; 1.0080x over previous
//
#include <hip/hip_runtime.h>
#include <hip/hip_bf16.h>

#define HH 1024
#define LL 2048
#define BB 8
#define NN2 32     // complex modes
#define CT 128     // chunk size
#define NCH 16     // LL / CT

typedef short bf16x8 __attribute__((ext_vector_type(8)));
typedef float f32x4  __attribute__((ext_vector_type(4)));

static __device__ __forceinline__ unsigned short bfbits(float x) {
    __hip_bfloat16 h = __float2bfloat16(x);
    return *(unsigned short*)&h;
}
static __device__ __forceinline__ float f_from_bits(unsigned short b) {
    __hip_bfloat16 h; *(unsigned short*)&h = b; return __bfloat162float(h);
}
// exp(dA * p), native ops, explicit range reduction.
static __device__ __forceinline__ float2 cexp_n(float2 dA, float p) {
    float mag = __expf(dA.x * p);
    float rev = dA.y * p * 0.15915494309f;
    rev -= floorf(rev);
    float ang = rev * 6.28318530718f;
    return make_float2(mag * __cosf(ang), mag * __sinf(ang));
}

#define SWZ(off, row) ((off) ^ (((row) & 7) << 4))

// ---------------------------------------------------------------------------
// Kernel 0: per-h tables -> global, PRE-SWIZZLED for global_load_lds staging.
// AJ_g[h]: 16KB  rows 2n/2n+1 (re/im), AJ[.][j] = a^(127-j)   (64x128 bf16)
// AP_g[h]: 16KB  AP[tt][2n]=2Re a^(tt+1), [2n+1]=-2Im         (128x64 bf16)
// misc_g[h]: 256 floats = kt[128] | Cn interleaved[64] | a^128 interleaved[64]
// ---------------------------------------------------------------------------
__global__ __launch_bounds__(256) void aux_tables(
    const float* __restrict__ log_dt, const float* __restrict__ log_w_real,
    const float* __restrict__ w_imag, const float* __restrict__ C_re,
    const float* __restrict__ C_im,
    __hip_bfloat16* __restrict__ AJ_g, __hip_bfloat16* __restrict__ AP_g,
    float* __restrict__ misc_g)
{
    __shared__ float2 dtA_s[NN2];
    __shared__ float2 Cn_s[NN2];
    const int tid = threadIdx.x;
    const int h = blockIdx.x;

    if (tid < NN2) {
        int n = tid;
        float dt = expf(log_dt[h]);
        float wr = -expf(log_w_real[n]);
        float wi = w_imag[n];
        float dar = wr * dt, dai = wi * dt;
        dtA_s[n] = make_float2(dar, dai);
        float er = expf(dar);
        float sn, cs; sincosf(dai, &sn, &cs);
        float exr = er * cs - 1.0f, exi = er * sn;
        float den = wr * wr + wi * wi;
        float fr = (exr * wr + exi * wi) / den;
        float fi = (exi * wr - exr * wi) / den;
        float cre = C_re[h * NN2 + n], cim = C_im[h * NN2 + n];
        float2 Cv = make_float2(cre * fr - cim * fi, cre * fi + cim * fr);
        Cn_s[n] = Cv;
        misc_g[h * 256 + 128 + 2 * n]     = Cv.x;
        misc_g[h * 256 + 128 + 2 * n + 1] = Cv.y;
        float magA = expf(dar * 128.0f);
        float snA, csA; sincosf(dai * 128.0f, &snA, &csA);
        misc_g[h * 256 + 192 + 2 * n]     = magA * csA;
        misc_g[h * 256 + 192 + 2 * n + 1] = magA * snA;
    }
    __syncthreads();

    char* ajb = (char*)AJ_g + (size_t)h * 16384;
    #pragma unroll
    for (int q = 0; q < 2; ++q) {
        int task = q * 256 + tid;              // 512 tasks: (n, j0 block of 8)
        int n = task >> 4, j0 = (task & 15) * 8;
        float2 dA = dtA_s[n];
        unsigned rw[4], iw[4];
        #pragma unroll
        for (int i2 = 0; i2 < 4; ++i2) {
            float2 a0 = cexp_n(dA, (float)(127 - j0 - 2 * i2));
            float2 a1 = cexp_n(dA, (float)(127 - j0 - 2 * i2 - 1));
            rw[i2] = (unsigned)bfbits(a0.x) | ((unsigned)bfbits(a1.x) << 16);
            iw[i2] = (unsigned)bfbits(a0.y) | ((unsigned)bfbits(a1.y) << 16);
        }
        int r0 = 2 * n, r1 = 2 * n + 1;
        *(uint4*)(ajb + SWZ(r0 * 256 + j0 * 2, r0)) = make_uint4(rw[0], rw[1], rw[2], rw[3]);
        *(uint4*)(ajb + SWZ(r1 * 256 + j0 * 2, r1)) = make_uint4(iw[0], iw[1], iw[2], iw[3]);
    }

    char* apb = (char*)AP_g + (size_t)h * 16384;
    #pragma unroll
    for (int q = 0; q < 2; ++q) {
        int task = q * 256 + tid;              // 512 tasks: (ttr, n0 block of 8)
        int ttr = task >> 2, n0 = (task & 3) * 8;
        unsigned w[8];
        #pragma unroll
        for (int i = 0; i < 8; ++i) {
            float2 a = cexp_n(dtA_s[n0 + i], (float)(ttr + 1));
            w[i] = (unsigned)bfbits(2.0f * a.x) | ((unsigned)bfbits(-2.0f * a.y) << 16);
        }
        *(uint4*)(apb + SWZ(ttr * 128 + n0 * 4, ttr))      = make_uint4(w[0], w[1], w[2], w[3]);
        *(uint4*)(apb + SWZ(ttr * 128 + n0 * 4 + 16, ttr)) = make_uint4(w[4], w[5], w[6], w[7]);
    }

    {   // kt[t] = 2 Re sum_n Cn a^t : 2 threads per tap
        int t = tid >> 1, nb = (tid & 1) * 16;
        float s = 0.f;
        #pragma unroll
        for (int i = 0; i < 16; ++i) {
            int n = nb + i;
            float2 a = cexp_n(dtA_s[n], (float)t);
            float2 C = Cn_s[n];
            s += C.x * a.x - C.y * a.y;
        }
        s += __shfl_xor(s, 1);
        if ((tid & 1) == 0) misc_g[h * 256 + t] = 2.0f * s;
    }
}

// ---------------- ssm LDS pool offsets (bytes), 8-batch version -------------
#define S_U    0        // ushort U[128][128] swz (32768)
#define S_UN   32768    // 16KB union: AJ[64][128] -> K1/K2[128][64] -> AP[128][64]
#define S_P    49152    // ushort P/CS[128][64] swz (16384)
#define S_KT   65536    // kt[128] f32 | Cn f2[32] | A128 f2[32]  (1024)
#define S_TOT  66560

// K build from kt: K[ttr][j] = kt[ttr - hf*64 - j] (or 0)
#define KBUILD(hf)                                                       \
    _Pragma("unroll")                                                    \
    for (int q = 0; q < 4; ++q) {                                        \
        int idx = q * 512 + tid;                                         \
        int ttr = idx >> 4, j0 = (idx & 15) * 4;                         \
        int base = ttr - (hf) * 64 - j0;                                 \
        ushort4 o;                                                       \
        o.x = (base     >= 0) ? bfbits(kt[base])     : (unsigned short)0;\
        o.y = (base - 1 >= 0) ? bfbits(kt[base - 1]) : (unsigned short)0;\
        o.z = (base - 2 >= 0) ? bfbits(kt[base - 2]) : (unsigned short)0;\
        o.w = (base - 3 >= 0) ? bfbits(kt[base - 3]) : (unsigned short)0;\
        *(ushort4*)(smem + SWZ(S_UN + ttr * 128 + j0 * 2, ttr)) = o;     \
    }

// ---------------------------------------------------------------------------
// Kernel 1: ONE block per h, all 8 batches (tables staged once per h).
// 512 thr, 65KB LDS -> 2 blocks/CU.
// ---------------------------------------------------------------------------
__global__ __launch_bounds__(512, 4) void ssm_mfma(
    const float* __restrict__ u,
    const __hip_bfloat16* __restrict__ AJ_g,
    const __hip_bfloat16* __restrict__ AP_g,
    const float* __restrict__ misc_g,
    const float* __restrict__ Dp, __hip_bfloat16* __restrict__ g_out)
{
    extern __shared__ char smem[];
    float*  kt   = (float*)(smem + S_KT);
    float2* CnL  = (float2*)(smem + S_KT + 512);
    float2* A128 = (float2*)(smem + S_KT + 768);

    const int tid  = threadIdx.x;
    const int lane = tid & 63;
    const int wave = tid >> 6;
    const int wr4  = wave >> 1;     // 0..3 : 32 bc-rows each
    const int wc2  = wave & 1;      // 0..1 : column halves
    const int h    = blockIdx.x;

    // ---- issue table staging (AJ 16KB -> S_UN, misc 1KB -> S_KT) ----------
    {
        const char* ajs = (const char*)AJ_g + (size_t)h * 16384;
        __builtin_amdgcn_global_load_lds(
            (const __attribute__((address_space(1))) void*)(ajs + tid * 16),
            (__attribute__((address_space(3))) void*)(smem + S_UN + wave * 1024), 16, 0, 0);
        __builtin_amdgcn_global_load_lds(
            (const __attribute__((address_space(1))) void*)(ajs + 8192 + tid * 16),
            (__attribute__((address_space(3))) void*)(smem + S_UN + 8192 + wave * 1024), 16, 0, 0);
        if (tid < 64) {
            const char* ms = (const char*)misc_g + (size_t)h * 1024;
            __builtin_amdgcn_global_load_lds(
                (const __attribute__((address_space(1))) void*)(ms + tid * 16),
                (__attribute__((address_space(3))) void*)(smem + S_KT), 16, 0, 0);
        }
    }

    // ---- u load (8 batches) + bf16 convert -> U LDS -----------------------
    float4 ureg[8];
    #pragma unroll
    for (int q = 0; q < 8; ++q)
        ureg[q] = *(const float4*)(u + ((size_t)(q * HH + h)) * LL + tid * 4);
    #pragma unroll
    for (int q = 0; q < 8; ++q) {
        int row = q * 16 + (tid >> 5);          // bc row (8 batches x 16 chunks)
        int j   = (tid & 31) * 4;
        ushort4 o;
        o.x = bfbits(ureg[q].x); o.y = bfbits(ureg[q].y);
        o.z = bfbits(ureg[q].z); o.w = bfbits(ureg[q].w);
        *(ushort4*)(smem + SWZ(S_U + row * 256 + j * 2, row)) = o;
    }
    asm volatile("s_waitcnt vmcnt(0)" ::: "memory");
    __syncthreads();                                         // [1] AJ/misc/U ready

    // ---- ph1: partials GEMM P[bc 128][n' 64] = U x AJ, K=128 --------------
    f32x4 accP[2][2] = {};
    #pragma unroll
    for (int ks = 0; ks < 4; ++ks) {
        int kf = ks * 32 + (lane >> 4) * 8;
        bf16x8 a0, a1, b0, b1;
        {
            int r = wr4 * 32 + (lane & 15);
            a0 = *(bf16x8*)(smem + SWZ(S_U + r * 256 + kf * 2, r));
            int r2 = r + 16;
            a1 = *(bf16x8*)(smem + SWZ(S_U + r2 * 256 + kf * 2, r2));
        }
        {
            int r = wc2 * 32 + (lane & 15);
            b0 = *(bf16x8*)(smem + SWZ(S_UN + r * 256 + kf * 2, r));
            int r2 = r + 16;
            b1 = *(bf16x8*)(smem + SWZ(S_UN + r2 * 256 + kf * 2, r2));
        }
        accP[0][0] = __builtin_amdgcn_mfma_f32_16x16x32_bf16(a0, b0, accP[0][0], 0, 0, 0);
        accP[0][1] = __builtin_amdgcn_mfma_f32_16x16x32_bf16(a0, b1, accP[0][1], 0, 0, 0);
        accP[1][0] = __builtin_amdgcn_mfma_f32_16x16x32_bf16(a1, b0, accP[1][0], 0, 0, 0);
        accP[1][1] = __builtin_amdgcn_mfma_f32_16x16x32_bf16(a1, b1, accP[1][1], 0, 0, 0);
    }
    #pragma unroll
    for (int mt = 0; mt < 2; ++mt)
        #pragma unroll
        for (int nt = 0; nt < 2; ++nt)
            #pragma unroll
            for (int r = 0; r < 4; ++r) {
                int row = wr4 * 32 + mt * 16 + (lane >> 4) * 4 + r;
                int col = wc2 * 32 + nt * 16 + (lane & 15);
                *(unsigned short*)(smem + SWZ(S_P + row * 128 + col * 2, row)) =
                    bfbits(accP[mt][nt][r]);
            }
    __syncthreads();                                         // [2] AJ consumed, P ready

    // ---- ph2: K1 build + scan (tid<256: 8b x 32n) -------------------------
    KBUILD(0)
    if (tid < 256) {
        int b = tid >> 5, n = tid & 31;
        float2 C = CnL[n];
        float2 A = A128[n];
        float sr = 0.f, si = 0.f;
        for (int c = 0; c < NCH; ++c) {
            int row = b * 16 + c;
            int off = SWZ(S_P + row * 128 + n * 4, row);
            unsigned int pv = *(unsigned int*)(smem + off);
            float pr = f_from_bits((unsigned short)(pv & 0xffff));
            float pi = f_from_bits((unsigned short)(pv >> 16));
            float csr = C.x * sr - C.y * si;
            float csi = C.x * si + C.y * sr;
            *(unsigned int*)(smem + off) =
                (unsigned)bfbits(csr) | ((unsigned)bfbits(csi) << 16);
            float nsr = A.x * sr - A.y * si + pr;
            float nsi = A.x * si + A.y * sr + pi;
            sr = nsr; si = nsi;
        }
    }
    __syncthreads();                                         // [3] K1/CS ready

    // ---- ph3a: conv GEMM half 1 (j in [0,64)) -----------------------------
    f32x4 acc[2][4] = {};
    #pragma unroll
    for (int ks = 0; ks < 2; ++ks) {
        int kf = ks * 32 + (lane >> 4) * 8;
        bf16x8 a0, a1, bv[4];
        {
            int r = wr4 * 32 + (lane & 15);
            a0 = *(bf16x8*)(smem + SWZ(S_U + r * 256 + kf * 2, r));
            int r2 = r + 16;
            a1 = *(bf16x8*)(smem + SWZ(S_U + r2 * 256 + kf * 2, r2));
        }
        #pragma unroll
        for (int nt = 0; nt < 4; ++nt) {
            int ttr = wc2 * 64 + nt * 16 + (lane & 15);
            bv[nt] = *(bf16x8*)(smem + SWZ(S_UN + ttr * 128 + kf * 2, ttr));
        }
        #pragma unroll
        for (int nt = 0; nt < 4; ++nt) {
            acc[0][nt] = __builtin_amdgcn_mfma_f32_16x16x32_bf16(a0, bv[nt], acc[0][nt], 0, 0, 0);
            acc[1][nt] = __builtin_amdgcn_mfma_f32_16x16x32_bf16(a1, bv[nt], acc[1][nt], 0, 0, 0);
        }
    }
    __syncthreads();                                         // [4] K1 consumed

    // ---- ph3b: K2 build + conv GEMM half 2 --------------------------------
    KBUILD(1)
    __syncthreads();                                         // [5] K2 ready
    #pragma unroll
    for (int ks = 0; ks < 2; ++ks) {
        int kf = ks * 32 + (lane >> 4) * 8;
        bf16x8 a0, a1, bv[4];
        {
            int r = wr4 * 32 + (lane & 15);
            a0 = *(bf16x8*)(smem + SWZ(S_U + r * 256 + 128 + kf * 2, r));
            int r2 = r + 16;
            a1 = *(bf16x8*)(smem + SWZ(S_U + r2 * 256 + 128 + kf * 2, r2));
        }
        #pragma unroll
        for (int nt = 0; nt < 4; ++nt) {
            int ttr = wc2 * 64 + nt * 16 + (lane & 15);
            bv[nt] = *(bf16x8*)(smem + SWZ(S_UN + ttr * 128 + kf * 2, ttr));
        }
        #pragma unroll
        for (int nt = 0; nt < 4; ++nt) {
            acc[0][nt] = __builtin_amdgcn_mfma_f32_16x16x32_bf16(a0, bv[nt], acc[0][nt], 0, 0, 0);
            acc[1][nt] = __builtin_amdgcn_mfma_f32_16x16x32_bf16(a1, bv[nt], acc[1][nt], 0, 0, 0);
        }
    }
    __syncthreads();                                         // [6] K2 consumed, UN free

    // ---- stage AP -> S_UN, then state GEMM --------------------------------
    {
        const char* aps = (const char*)AP_g + (size_t)h * 16384;
        __builtin_amdgcn_global_load_lds(
            (const __attribute__((address_space(1))) void*)(aps + tid * 16),
            (__attribute__((address_space(3))) void*)(smem + S_UN + wave * 1024), 16, 0, 0);
        __builtin_amdgcn_global_load_lds(
            (const __attribute__((address_space(1))) void*)(aps + 8192 + tid * 16),
            (__attribute__((address_space(3))) void*)(smem + S_UN + 8192 + wave * 1024), 16, 0, 0);
    }
    asm volatile("s_waitcnt vmcnt(0)" ::: "memory");
    __syncthreads();                                         // [7] AP ready

    #pragma unroll
    for (int ks = 0; ks < 2; ++ks) {
        int kf = ks * 32 + (lane >> 4) * 8;
        bf16x8 a0, a1, bv[4];
        {
            int r = wr4 * 32 + (lane & 15);
            a0 = *(bf16x8*)(smem + SWZ(S_P + r * 128 + kf * 2, r));
            int r2 = r + 16;
            a1 = *(bf16x8*)(smem + SWZ(S_P + r2 * 128 + kf * 2, r2));
        }
        #pragma unroll
        for (int nt = 0; nt < 4; ++nt) {
            int ttr = wc2 * 64 + nt * 16 + (lane & 15);
            bv[nt] = *(bf16x8*)(smem + SWZ(S_UN + ttr * 128 + kf * 2, ttr));
        }
        #pragma unroll
        for (int nt = 0; nt < 4; ++nt) {
            acc[0][nt] = __builtin_amdgcn_mfma_f32_16x16x32_bf16(a0, bv[nt], acc[0][nt], 0, 0, 0);
            acc[1][nt] = __builtin_amdgcn_mfma_f32_16x16x32_bf16(a1, bv[nt], acc[1][nt], 0, 0, 0);
        }
    }

    // ---- epilogue: y = acc + D*u, GELU -> LDS -> packed stores ------------
    const float Dv = Dp[h];
    #pragma unroll
    for (int mt = 0; mt < 2; ++mt)
        #pragma unroll
        for (int nt = 0; nt < 4; ++nt)
            #pragma unroll
            for (int r = 0; r < 4; ++r) {
                int row = wr4 * 32 + mt * 16 + (lane >> 4) * 4 + r;
                int ttr = wc2 * 64 + nt * 16 + (lane & 15);
                int off = SWZ(S_U + row * 256 + ttr * 2, row);
                float uv = f_from_bits(*(unsigned short*)(smem + off));
                float y = acc[mt][nt][r] + Dv * uv;
                float z = 0.7978845608f * (y + 0.044715f * y * y * y);
                float e = __expf(2.0f * z);
                float th = 1.0f - 2.0f / (e + 1.0f);
                float gel = 0.5f * y * (1.0f + th);
                *(unsigned short*)(smem + off) = bfbits(gel);
            }
    __syncthreads();                                         // [8]
    #pragma unroll
    for (int q = 0; q < 4; ++q) {
        int flat = q * 512 + tid;               // 2048 uint4 tiles
        int row = flat >> 4, c16 = flat & 15;
        uint4 v = *(uint4*)(smem + SWZ(S_U + row * 256 + c16 * 16, row));
        int b = row >> 4, c = row & 15;
        *(uint4*)(g_out + ((size_t)(b * HH + h)) * LL + c * CT + c16 * 8) = v;
    }
}

// ---------------------------------------------------------------------------
// Kernel 2: W (1024x1024 fp32) -> bf16
// ---------------------------------------------------------------------------
__global__ __launch_bounds__(256) void conv_w(
    const float* __restrict__ W, __hip_bfloat16* __restrict__ Wb)
{
    int i = blockIdx.x * 256 + threadIdx.x;
    float4 v = ((const float4*)W)[i];
    ushort4 o;
    o.x = bfbits(v.x); o.y = bfbits(v.y); o.z = bfbits(v.z); o.w = bfbits(v.w);
    ((ushort4*)Wb)[i] = o;
}

// ---------------------------------------------------------------------------
// Kernel 3: transpose g (B,H,L) bf16 -> gT (B,L,H) bf16
// ---------------------------------------------------------------------------
__global__ __launch_bounds__(256) void transpose_g(
    const __hip_bfloat16* __restrict__ g, __hip_bfloat16* __restrict__ gT)
{
    __shared__ __hip_bfloat16 t[64][66];
    const int tid = threadIdx.x;
    const int b  = blockIdx.z;
    const int h0 = blockIdx.x * 64;
    const int l0 = blockIdx.y * 64;

    #pragma unroll
    for (int q = 0; q < 2; ++q) {
        int idx = tid + q * 256;
        int r = idx >> 3, c8 = (idx & 7) * 8;
        uint4 v = *(const uint4*)(g + ((size_t)(b * HH + h0 + r)) * LL + l0 + c8);
        unsigned int* dst = (unsigned int*)&t[r][c8];
        dst[0] = v.x; dst[1] = v.y; dst[2] = v.z; dst[3] = v.w;
    }
    __syncthreads();
    #pragma unroll
    for (int q = 0; q < 2; ++q) {
        int idx = tid + q * 256;
        int r = idx >> 3, c8 = (idx & 7) * 8;
        unsigned short tmp[8];
        #pragma unroll
        for (int j = 0; j < 8; ++j) tmp[j] = *(unsigned short*)&t[c8 + j][r];
        uint4 o;
        o.x = (unsigned)tmp[0] | ((unsigned)tmp[1] << 16);
        o.y = (unsigned)tmp[2] | ((unsigned)tmp[3] << 16);
        o.z = (unsigned)tmp[4] | ((unsigned)tmp[5] << 16);
        o.w = (unsigned)tmp[6] | ((unsigned)tmp[7] << 16);
        *(uint4*)(gT + ((size_t)(b * LL + l0 + r)) * HH + h0 + c8) = o;
    }
}

// ---------------------------------------------------------------------------
// Kernel 4: out = Wb x gT^T + bias (unchanged)
// ---------------------------------------------------------------------------
#define GSLOT 32768
#define STAGE_TILE(kt_, s_)                                                      \
    {                                                                            \
        const int k0_ = (kt_) * 64;                                              \
        _Pragma("unroll")                                                        \
        for (int v_ = 0; v_ < 4; ++v_) {                                         \
            int row_ = v_ * 64 + rsub;                                           \
            const __hip_bfloat16* ga_ = Wb + (size_t)(o0 + row_) * HH + k0_ + csw; \
            const __hip_bfloat16* gb_ = gT + (size_t)(n0 + row_) * HH + k0_ + csw; \
            char* dA_ = smem + (s_) * GSLOT + (v_ * 64 + wave * 8) * 128;        \
            char* dB_ = smem + 2 * GSLOT + (s_) * GSLOT + (v_ * 64 + wave * 8) * 128; \
            __builtin_amdgcn_global_load_lds(                                    \
                (const __attribute__((address_space(1))) void*)ga_,              \
                (__attribute__((address_space(3))) void*)dA_, 16, 0, 0);         \
            __builtin_amdgcn_global_load_lds(                                    \
                (const __attribute__((address_space(1))) void*)gb_,              \
                (__attribute__((address_space(3))) void*)dB_, 16, 0, 0);         \
        }                                                                        \
    }

#define COMPUTE_TILE(s_)                                                         \
    {                                                                            \
        const char* baseA = smem + (s_) * GSLOT;                                 \
        const char* baseB = smem + 2 * GSLOT + (s_) * GSLOT;                     \
        bf16x8 bfr[4][2];                                                        \
        _Pragma("unroll")                                                        \
        for (int nt = 0; nt < 4; ++nt)                                           \
            _Pragma("unroll")                                                    \
            for (int ks = 0; ks < 2; ++ks) {                                     \
                int rb = wn * 64 + nt * 16 + (lane & 15);                        \
                int c  = (ks * 32 + (lane >> 4) * 8) ^ ((rb & 7) << 3);          \
                bfr[nt][ks] = *(const bf16x8*)(baseB + rb * 128 + c * 2);        \
            }                                                                    \
        _Pragma("unroll")                                                        \
        for (int qq = 0; qq < 4; ++qq) {                                         \
            bf16x8 af[2][2];                                                     \
            _Pragma("unroll")                                                    \
            for (int mt = 0; mt < 2; ++mt)                                       \
                _Pragma("unroll")                                                \
                for (int ks = 0; ks < 2; ++ks) {                                 \
                    int ra = wm * 128 + (qq * 2 + mt) * 16 + (lane & 15);        \
                    int c  = (ks * 32 + (lane >> 4) * 8) ^ ((ra & 7) << 3);      \
                    af[mt][ks] = *(const bf16x8*)(baseA + ra * 128 + c * 2);     \
                }                                                                \
            __builtin_amdgcn_s_setprio(1);                                       \
            _Pragma("unroll")                                                    \
            for (int mt = 0; mt < 2; ++mt)                                       \
                _Pragma("unroll")                                                \
                for (int nt = 0; nt < 4; ++nt) {                                 \
                    acc[qq * 2 + mt][nt] = __builtin_amdgcn_mfma_f32_16x16x32_bf16( \
                        af[mt][0], bfr[nt][0], acc[qq * 2 + mt][nt], 0, 0, 0);   \
                    acc[qq * 2 + mt][nt] = __builtin_amdgcn_mfma_f32_16x16x32_bf16( \
                        af[mt][1], bfr[nt][1], acc[qq * 2 + mt][nt], 0, 0, 0);   \
                }                                                                \
            __builtin_amdgcn_s_setprio(0);                                       \
        }                                                                        \
    }

__global__ __launch_bounds__(512, 2) void out_gemm_256(
    const __hip_bfloat16* __restrict__ Wb,
    const __hip_bfloat16* __restrict__ gT,
    const float* __restrict__ bias,
    float* __restrict__ out)
{
    extern __shared__ char smem[];
    const int tid  = threadIdx.x;
    const int lane = tid & 63;
    const int wave = tid >> 6;
    const int wm = wave >> 2;
    const int wn = wave & 3;

    int wg  = blockIdx.x;
    int swz = (wg & 7) * 32 + (wg >> 3);
    const int o0 = (swz & 3) * 256;
    const int n0 = (swz >> 2) * 256;

    const int rsub = tid >> 3;
    const int csw  = ((tid & 7) ^ (rsub & 7)) << 3;

    f32x4 acc[8][4] = {};

    STAGE_TILE(0, 0)
    STAGE_TILE(1, 1)

    for (int t = 0; t < 15; ++t) {
        asm volatile("s_waitcnt vmcnt(8)" ::: "memory");
        __builtin_amdgcn_s_barrier();
        __builtin_amdgcn_sched_barrier(0);
        COMPUTE_TILE(t & 1)
        asm volatile("s_waitcnt lgkmcnt(0)" ::: "memory");
        __builtin_amdgcn_s_barrier();
        __builtin_amdgcn_sched_barrier(0);
        if (t < 14) STAGE_TILE(t + 2, t & 1)
    }
    asm volatile("s_waitcnt vmcnt(0)" ::: "memory");
    __builtin_amdgcn_s_barrier();
    __builtin_amdgcn_sched_barrier(0);
    COMPUTE_TILE(1)

    const int bb = n0 >> 11;
    #pragma unroll
    for (int m = 0; m < 8; ++m) {
        int o = o0 + wm * 128 + m * 16 + (lane >> 4) * 4;
        #pragma unroll
        for (int nt = 0; nt < 4; ++nt) {
            int n = n0 + wn * 64 + nt * 16 + (lane & 15);
            int l = n & 2047;
            #pragma unroll
            for (int r = 0; r < 4; ++r)
                out[((size_t)(bb * HH + o + r)) * LL + l] = acc[m][nt][r] + bias[o + r];
        }
    }
}

extern "C" void kernel_launch(void* const* d_in, const int* in_sizes, int n_in,
                              void* d_out, int out_size, void* d_ws, size_t ws_size,
                              hipStream_t stream) {
    const float* u          = (const float*)d_in[0];
    const float* log_dt     = (const float*)d_in[1];
    const float* log_w_real = (const float*)d_in[2];
    const float* w_imag     = (const float*)d_in[3];
    const float* C_re       = (const float*)d_in[4];
    const float* C_im       = (const float*)d_in[5];
    const float* Dp         = (const float*)d_in[6];
    const float* W          = (const float*)d_in[7];
    const float* bias       = (const float*)d_in[8];
    float* out = (float*)d_out;

    // d_out (64 MiB) = [AJ 16 MiB][AP 16 MiB][g 32 MiB]  (all consumed before
    // the final GEMM overwrites every byte of d_out)
    __hip_bfloat16* AJ_g = (__hip_bfloat16*)d_out;
    __hip_bfloat16* AP_g = (__hip_bfloat16*)((char*)d_out + 16777216);
    __hip_bfloat16* g    = (__hip_bfloat16*)((char*)d_out + 33554432);
    // ws: gT 33.5MB | Wb 2MB | misc 1MB
    __hip_bfloat16* gT     = (__hip_bfloat16*)d_ws;
    __hip_bfloat16* Wb     = (__hip_bfloat16*)((char*)d_ws + 33554432);
    float*          misc_g = (float*)((char*)d_ws + 35651584);

    hipFuncSetAttribute((const void*)ssm_mfma,
                        hipFuncAttributeMaxDynamicSharedMemorySize, S_TOT);
    hipFuncSetAttribute((const void*)out_gemm_256,
                        hipFuncAttributeMaxDynamicSharedMemorySize, 131072);

    conv_w<<<dim3(HH * HH / 1024), 256, 0, stream>>>(W, Wb);
    aux_tables<<<dim3(HH), 256, 0, stream>>>(log_dt, log_w_real, w_imag,
                                             C_re, C_im, AJ_g, AP_g, misc_g);
    ssm_mfma<<<dim3(HH), 512, S_TOT, stream>>>(u, AJ_g, AP_g, misc_g, Dp, g);
    transpose_g<<<dim3(HH / 64, LL / 64, BB), 256, 0, stream>>>(g, gT);
    out_gemm_256<<<dim3(256), 512, 131072, stream>>>(Wb, gT, bias, out);
}

// Round 10
// 104.558 us; speedup vs baseline: 1.0932x; 1.0288x over previous
//
#include <hip/hip_runtime.h>
#include <hip/hip_bf16.h>

#define HH 1024
#define LL 2048
#define BB 8
#define NN2 32     // complex modes
#define CT 128     // chunk size
#define NCH 16     // LL / CT

typedef short bf16x8 __attribute__((ext_vector_type(8)));
typedef float f32x4  __attribute__((ext_vector_type(4)));

static __device__ __forceinline__ unsigned short bfbits(float x) {
    __hip_bfloat16 h = __float2bfloat16(x);
    return *(unsigned short*)&h;
}
static __device__ __forceinline__ float f_from_bits(unsigned short b) {
    __hip_bfloat16 h; *(unsigned short*)&h = b; return __bfloat162float(h);
}
// exp(dA * p), native ops, explicit range reduction.
static __device__ __forceinline__ float2 cexp_n(float2 dA, float p) {
    float mag = __expf(dA.x * p);
    float rev = dA.y * p * 0.15915494309f;
    rev -= floorf(rev);
    float ang = rev * 6.28318530718f;
    return make_float2(mag * __cosf(ang), mag * __sinf(ang));
}

#define SWZ(off, row) ((off) ^ (((row) & 7) << 4))

// ---------------------------------------------------------------------------
// Kernel 0: per-h tables -> global, PRE-SWIZZLED for global_load_lds staging.
// AJ_g[h]: 16KB  rows 2n/2n+1 (re/im), AJ[.][j] = a^(127-j)   (64x128 bf16)
// AP_g[h]: 16KB  AP[tt][2n]=2Re a^(tt+1), [2n+1]=-2Im         (128x64 bf16)
// misc_g[h]: 256 floats = kt[128] | Cn interleaved[64] | a^128 interleaved[64]
// ALSO converts W row h -> bf16 (merged conv_w).
// ---------------------------------------------------------------------------
__global__ __launch_bounds__(256) void aux_tables(
    const float* __restrict__ log_dt, const float* __restrict__ log_w_real,
    const float* __restrict__ w_imag, const float* __restrict__ C_re,
    const float* __restrict__ C_im, const float* __restrict__ W,
    __hip_bfloat16* __restrict__ AJ_g, __hip_bfloat16* __restrict__ AP_g,
    float* __restrict__ misc_g, __hip_bfloat16* __restrict__ Wb)
{
    __shared__ float2 dtA_s[NN2];
    __shared__ float2 Cn_s[NN2];
    const int tid = threadIdx.x;
    const int h = blockIdx.x;

    // merged conv_w: convert W row h (1024 floats, 1 float4/thread)
    {
        float4 v = ((const float4*)(W + (size_t)h * HH))[tid];
        ushort4 o;
        o.x = bfbits(v.x); o.y = bfbits(v.y); o.z = bfbits(v.z); o.w = bfbits(v.w);
        ((ushort4*)(Wb + (size_t)h * HH))[tid] = o;
    }

    if (tid < NN2) {
        int n = tid;
        float dt = expf(log_dt[h]);
        float wr = -expf(log_w_real[n]);
        float wi = w_imag[n];
        float dar = wr * dt, dai = wi * dt;
        dtA_s[n] = make_float2(dar, dai);
        float er = expf(dar);
        float sn, cs; sincosf(dai, &sn, &cs);
        float exr = er * cs - 1.0f, exi = er * sn;
        float den = wr * wr + wi * wi;
        float fr = (exr * wr + exi * wi) / den;
        float fi = (exi * wr - exr * wi) / den;
        float cre = C_re[h * NN2 + n], cim = C_im[h * NN2 + n];
        float2 Cv = make_float2(cre * fr - cim * fi, cre * fi + cim * fr);
        Cn_s[n] = Cv;
        misc_g[h * 256 + 128 + 2 * n]     = Cv.x;
        misc_g[h * 256 + 128 + 2 * n + 1] = Cv.y;
        float magA = expf(dar * 128.0f);
        float snA, csA; sincosf(dai * 128.0f, &snA, &csA);
        misc_g[h * 256 + 192 + 2 * n]     = magA * csA;
        misc_g[h * 256 + 192 + 2 * n + 1] = magA * snA;
    }
    __syncthreads();

    char* ajb = (char*)AJ_g + (size_t)h * 16384;
    #pragma unroll
    for (int q = 0; q < 2; ++q) {
        int task = q * 256 + tid;              // 512 tasks: (n, j0 block of 8)
        int n = task >> 4, j0 = (task & 15) * 8;
        float2 dA = dtA_s[n];
        unsigned rw[4], iw[4];
        #pragma unroll
        for (int i2 = 0; i2 < 4; ++i2) {
            float2 a0 = cexp_n(dA, (float)(127 - j0 - 2 * i2));
            float2 a1 = cexp_n(dA, (float)(127 - j0 - 2 * i2 - 1));
            rw[i2] = (unsigned)bfbits(a0.x) | ((unsigned)bfbits(a1.x) << 16);
            iw[i2] = (unsigned)bfbits(a0.y) | ((unsigned)bfbits(a1.y) << 16);
        }
        int r0 = 2 * n, r1 = 2 * n + 1;
        *(uint4*)(ajb + SWZ(r0 * 256 + j0 * 2, r0)) = make_uint4(rw[0], rw[1], rw[2], rw[3]);
        *(uint4*)(ajb + SWZ(r1 * 256 + j0 * 2, r1)) = make_uint4(iw[0], iw[1], iw[2], iw[3]);
    }

    char* apb = (char*)AP_g + (size_t)h * 16384;
    #pragma unroll
    for (int q = 0; q < 2; ++q) {
        int task = q * 256 + tid;              // 512 tasks: (ttr, n0 block of 8)
        int ttr = task >> 2, n0 = (task & 3) * 8;
        unsigned w[8];
        #pragma unroll
        for (int i = 0; i < 8; ++i) {
            float2 a = cexp_n(dtA_s[n0 + i], (float)(ttr + 1));
            w[i] = (unsigned)bfbits(2.0f * a.x) | ((unsigned)bfbits(-2.0f * a.y) << 16);
        }
        *(uint4*)(apb + SWZ(ttr * 128 + n0 * 4, ttr))      = make_uint4(w[0], w[1], w[2], w[3]);
        *(uint4*)(apb + SWZ(ttr * 128 + n0 * 4 + 16, ttr)) = make_uint4(w[4], w[5], w[6], w[7]);
    }

    {   // kt[t] = 2 Re sum_n Cn a^t : 2 threads per tap
        int t = tid >> 1, nb = (tid & 1) * 16;
        float s = 0.f;
        #pragma unroll
        for (int i = 0; i < 16; ++i) {
            int n = nb + i;
            float2 a = cexp_n(dtA_s[n], (float)t);
            float2 C = Cn_s[n];
            s += C.x * a.x - C.y * a.y;
        }
        s += __shfl_xor(s, 1);
        if ((tid & 1) == 0) misc_g[h * 256 + t] = 2.0f * s;
    }
}

// ---------------- ssm LDS pool offsets (bytes) ----------------
#define S_U    0        // ushort U[128][128] swz (32768)
#define S_UN   32768    // 16KB union: AJ[64][128] -> AP[128][64]
#define S_P    49152    // ushort P/CS[128][64] swz (16384)
#define S_KT   65536    // kt[128] f32 | Cn f2[32] | A128 f2[32]  (1024)
#define S_KTP  66560    // ktp8: 8 copies x 264 bf16, stride 528B (4224)
#define S_TOT  70784

// ---------------------------------------------------------------------------
// Kernel 1: ONE block per h, all 8 batches. 512 thr, ~69KB LDS -> 2 blocks/CU.
// Toeplitz conv via shift-replicated ktp8 table (no K build, no extra barriers);
// AP staged early into freed S_UN, latency hidden under scan+conv.
// ---------------------------------------------------------------------------
__global__ __launch_bounds__(512, 4) void ssm_mfma(
    const float* __restrict__ u,
    const __hip_bfloat16* __restrict__ AJ_g,
    const __hip_bfloat16* __restrict__ AP_g,
    const float* __restrict__ misc_g,
    const float* __restrict__ Dp, __hip_bfloat16* __restrict__ g_out)
{
    extern __shared__ char smem[];
    float*  kt   = (float*)(smem + S_KT);
    float2* CnL  = (float2*)(smem + S_KT + 512);
    float2* A128 = (float2*)(smem + S_KT + 768);

    const int tid  = threadIdx.x;
    const int lane = tid & 63;
    const int wave = tid >> 6;
    const int wr4  = wave >> 1;     // 0..3 : 32 bc-rows each
    const int wc2  = wave & 1;      // 0..1 : column halves
    const int h    = blockIdx.x;

    // ---- issue table staging (AJ 16KB -> S_UN, misc 1KB -> S_KT) ----------
    {
        const char* ajs = (const char*)AJ_g + (size_t)h * 16384;
        __builtin_amdgcn_global_load_lds(
            (const __attribute__((address_space(1))) void*)(ajs + tid * 16),
            (__attribute__((address_space(3))) void*)(smem + S_UN + wave * 1024), 16, 0, 0);
        __builtin_amdgcn_global_load_lds(
            (const __attribute__((address_space(1))) void*)(ajs + 8192 + tid * 16),
            (__attribute__((address_space(3))) void*)(smem + S_UN + 8192 + wave * 1024), 16, 0, 0);
        if (tid < 64) {
            const char* ms = (const char*)misc_g + (size_t)h * 1024;
            __builtin_amdgcn_global_load_lds(
                (const __attribute__((address_space(1))) void*)(ms + tid * 16),
                (__attribute__((address_space(3))) void*)(smem + S_KT), 16, 0, 0);
        }
    }

    // ---- u load (8 batches) + bf16 convert -> U LDS -----------------------
    float4 ureg[8];
    #pragma unroll
    for (int q = 0; q < 8; ++q)
        ureg[q] = *(const float4*)(u + ((size_t)(q * HH + h)) * LL + tid * 4);
    #pragma unroll
    for (int q = 0; q < 8; ++q) {
        int row = q * 16 + (tid >> 5);          // bc row (8 batches x 16 chunks)
        int j   = (tid & 31) * 4;
        ushort4 o;
        o.x = bfbits(ureg[q].x); o.y = bfbits(ureg[q].y);
        o.z = bfbits(ureg[q].z); o.w = bfbits(ureg[q].w);
        *(ushort4*)(smem + SWZ(S_U + row * 256 + j * 2, row)) = o;
    }
    asm volatile("s_waitcnt vmcnt(0)" ::: "memory");
    __syncthreads();                                         // [1] AJ/misc/U ready

    // ---- build ktp8 (shift-replicated reversed kt, bf16) -------------------
    // ktp8[s][i] = (s+i <= 127) ? kt[127-s-i] : 0,  i in [0,264)
    {
        int s = wave;            // 8 waves = 8 copies
        int i0 = lane * 4;       // entries i0..i0+3 (0..255)
        ushort4 o;
        #pragma unroll
        for (int k = 0; k < 4; ++k) {
            int src = 127 - s - (i0 + k);
            ((unsigned short*)&o)[k] = (src >= 0) ? bfbits(kt[src]) : (unsigned short)0;
        }
        *(ushort4*)(smem + S_KTP + s * 528 + i0 * 2) = o;
        if (lane < 2) {          // entries 256..263: always zero
            *(ushort4*)(smem + S_KTP + s * 528 + 512 + lane * 8) = make_ushort4(0, 0, 0, 0);
        }
    }

    // ---- ph1: partials GEMM P[bc 128][n' 64] = U x AJ, K=128 --------------
    f32x4 accP[2][2] = {};
    #pragma unroll
    for (int ks = 0; ks < 4; ++ks) {
        int kf = ks * 32 + (lane >> 4) * 8;
        bf16x8 a0, a1, b0, b1;
        {
            int r = wr4 * 32 + (lane & 15);
            a0 = *(bf16x8*)(smem + SWZ(S_U + r * 256 + kf * 2, r));
            int r2 = r + 16;
            a1 = *(bf16x8*)(smem + SWZ(S_U + r2 * 256 + kf * 2, r2));
        }
        {
            int r = wc2 * 32 + (lane & 15);
            b0 = *(bf16x8*)(smem + SWZ(S_UN + r * 256 + kf * 2, r));
            int r2 = r + 16;
            b1 = *(bf16x8*)(smem + SWZ(S_UN + r2 * 256 + kf * 2, r2));
        }
        accP[0][0] = __builtin_amdgcn_mfma_f32_16x16x32_bf16(a0, b0, accP[0][0], 0, 0, 0);
        accP[0][1] = __builtin_amdgcn_mfma_f32_16x16x32_bf16(a0, b1, accP[0][1], 0, 0, 0);
        accP[1][0] = __builtin_amdgcn_mfma_f32_16x16x32_bf16(a1, b0, accP[1][0], 0, 0, 0);
        accP[1][1] = __builtin_amdgcn_mfma_f32_16x16x32_bf16(a1, b1, accP[1][1], 0, 0, 0);
    }
    #pragma unroll
    for (int mt = 0; mt < 2; ++mt)
        #pragma unroll
        for (int nt = 0; nt < 2; ++nt)
            #pragma unroll
            for (int r = 0; r < 4; ++r) {
                int row = wr4 * 32 + mt * 16 + (lane >> 4) * 4 + r;
                int col = wc2 * 32 + nt * 16 + (lane & 15);
                *(unsigned short*)(smem + SWZ(S_P + row * 128 + col * 2, row)) =
                    bfbits(accP[mt][nt][r]);
            }
    __syncthreads();                            // [2] AJ+ktp8 ready, P stored

    // ---- issue AP staging EARLY into freed S_UN (hides under scan+conv) ----
    {
        const char* aps = (const char*)AP_g + (size_t)h * 16384;
        __builtin_amdgcn_global_load_lds(
            (const __attribute__((address_space(1))) void*)(aps + tid * 16),
            (__attribute__((address_space(3))) void*)(smem + S_UN + wave * 1024), 16, 0, 0);
        __builtin_amdgcn_global_load_lds(
            (const __attribute__((address_space(1))) void*)(aps + 8192 + tid * 16),
            (__attribute__((address_space(3))) void*)(smem + S_UN + 8192 + wave * 1024), 16, 0, 0);
    }

    // ---- scan (waves 0-3) ---------------------------------------------------
    if (tid < 256) {
        int b = tid >> 5, n = tid & 31;
        float2 C = CnL[n];
        float2 A = A128[n];
        float sr = 0.f, si = 0.f;
        for (int c = 0; c < NCH; ++c) {
            int row = b * 16 + c;
            int off = SWZ(S_P + row * 128 + n * 4, row);
            unsigned int pv = *(unsigned int*)(smem + off);
            float pr = f_from_bits((unsigned short)(pv & 0xffff));
            float pi = f_from_bits((unsigned short)(pv >> 16));
            float csr = C.x * sr - C.y * si;
            float csi = C.x * si + C.y * sr;
            *(unsigned int*)(smem + off) =
                (unsigned)bfbits(csr) | ((unsigned)bfbits(csi) << 16);
            float nsr = A.x * sr - A.y * si + pr;
            float nsi = A.x * si + A.y * sr + pi;
            sr = nsr; si = nsi;
        }
    }

    // ---- conv GEMM (full K=128, Toeplitz B from ktp8) ----------------------
    f32x4 acc[2][4] = {};
    #pragma unroll
    for (int ks = 0; ks < 4; ++ks) {
        int kf = ks * 32 + (lane >> 4) * 8;
        bf16x8 a0, a1, bv[4];
        {
            int r = wr4 * 32 + (lane & 15);
            a0 = *(bf16x8*)(smem + SWZ(S_U + r * 256 + kf * 2, r));
            int r2 = r + 16;
            a1 = *(bf16x8*)(smem + SWZ(S_U + r2 * 256 + kf * 2, r2));
        }
        #pragma unroll
        for (int nt = 0; nt < 4; ++nt) {
            int ttr = wc2 * 64 + nt * 16 + (lane & 15);
            int s   = (127 - ttr) & 7;
            int gq  = (127 - ttr + kf) >> 3;
            bv[nt] = *(bf16x8*)(smem + S_KTP + s * 528 + gq * 16);
        }
        #pragma unroll
        for (int nt = 0; nt < 4; ++nt) {
            acc[0][nt] = __builtin_amdgcn_mfma_f32_16x16x32_bf16(a0, bv[nt], acc[0][nt], 0, 0, 0);
            acc[1][nt] = __builtin_amdgcn_mfma_f32_16x16x32_bf16(a1, bv[nt], acc[1][nt], 0, 0, 0);
        }
    }
    asm volatile("s_waitcnt vmcnt(0)" ::: "memory");         // AP landed
    __syncthreads();                                         // [3] CS + AP ready

    // ---- ph4: state GEMM (A = CS in S_P, B = AP in S_UN) -------------------
    #pragma unroll
    for (int ks = 0; ks < 2; ++ks) {
        int kf = ks * 32 + (lane >> 4) * 8;
        bf16x8 a0, a1, bv[4];
        {
            int r = wr4 * 32 + (lane & 15);
            a0 = *(bf16x8*)(smem + SWZ(S_P + r * 128 + kf * 2, r));
            int r2 = r + 16;
            a1 = *(bf16x8*)(smem + SWZ(S_P + r2 * 128 + kf * 2, r2));
        }
        #pragma unroll
        for (int nt = 0; nt < 4; ++nt) {
            int ttr = wc2 * 64 + nt * 16 + (lane & 15);
            bv[nt] = *(bf16x8*)(smem + SWZ(S_UN + ttr * 128 + kf * 2, ttr));
        }
        #pragma unroll
        for (int nt = 0; nt < 4; ++nt) {
            acc[0][nt] = __builtin_amdgcn_mfma_f32_16x16x32_bf16(a0, bv[nt], acc[0][nt], 0, 0, 0);
            acc[1][nt] = __builtin_amdgcn_mfma_f32_16x16x32_bf16(a1, bv[nt], acc[1][nt], 0, 0, 0);
        }
    }

    // ---- epilogue: y = acc + D*u, GELU -> LDS -> packed stores ------------
    const float Dv = Dp[h];
    #pragma unroll
    for (int mt = 0; mt < 2; ++mt)
        #pragma unroll
        for (int nt = 0; nt < 4; ++nt)
            #pragma unroll
            for (int r = 0; r < 4; ++r) {
                int row = wr4 * 32 + mt * 16 + (lane >> 4) * 4 + r;
                int ttr = wc2 * 64 + nt * 16 + (lane & 15);
                int off = SWZ(S_U + row * 256 + ttr * 2, row);
                float uv = f_from_bits(*(unsigned short*)(smem + off));
                float y = acc[mt][nt][r] + Dv * uv;
                float z = 0.7978845608f * (y + 0.044715f * y * y * y);
                float e = __expf(2.0f * z);
                float th = 1.0f - 2.0f / (e + 1.0f);
                float gel = 0.5f * y * (1.0f + th);
                *(unsigned short*)(smem + off) = bfbits(gel);
            }
    __syncthreads();                                         // [4]
    #pragma unroll
    for (int q = 0; q < 4; ++q) {
        int flat = q * 512 + tid;               // 2048 uint4 tiles
        int row = flat >> 4, c16 = flat & 15;
        uint4 v = *(uint4*)(smem + SWZ(S_U + row * 256 + c16 * 16, row));
        int b = row >> 4, c = row & 15;
        *(uint4*)(g_out + ((size_t)(b * HH + h)) * LL + c * CT + c16 * 8) = v;
    }
}

// ---------------------------------------------------------------------------
// Kernel 3: transpose g (B,H,L) bf16 -> gT (B,L,H) bf16
// ---------------------------------------------------------------------------
__global__ __launch_bounds__(256) void transpose_g(
    const __hip_bfloat16* __restrict__ g, __hip_bfloat16* __restrict__ gT)
{
    __shared__ __hip_bfloat16 t[64][66];
    const int tid = threadIdx.x;
    const int b  = blockIdx.z;
    const int h0 = blockIdx.x * 64;
    const int l0 = blockIdx.y * 64;

    #pragma unroll
    for (int q = 0; q < 2; ++q) {
        int idx = tid + q * 256;
        int r = idx >> 3, c8 = (idx & 7) * 8;
        uint4 v = *(const uint4*)(g + ((size_t)(b * HH + h0 + r)) * LL + l0 + c8);
        unsigned int* dst = (unsigned int*)&t[r][c8];
        dst[0] = v.x; dst[1] = v.y; dst[2] = v.z; dst[3] = v.w;
    }
    __syncthreads();
    #pragma unroll
    for (int q = 0; q < 2; ++q) {
        int idx = tid + q * 256;
        int r = idx >> 3, c8 = (idx & 7) * 8;
        unsigned short tmp[8];
        #pragma unroll
        for (int j = 0; j < 8; ++j) tmp[j] = *(unsigned short*)&t[c8 + j][r];
        uint4 o;
        o.x = (unsigned)tmp[0] | ((unsigned)tmp[1] << 16);
        o.y = (unsigned)tmp[2] | ((unsigned)tmp[3] << 16);
        o.z = (unsigned)tmp[4] | ((unsigned)tmp[5] << 16);
        o.w = (unsigned)tmp[6] | ((unsigned)tmp[7] << 16);
        *(uint4*)(gT + ((size_t)(b * LL + l0 + r)) * HH + h0 + c8) = o;
    }
}

// ---------------------------------------------------------------------------
// Kernel 4: out = Wb x gT^T + bias (unchanged)
// ---------------------------------------------------------------------------
#define GSLOT 32768
#define STAGE_TILE(kt_, s_)                                                      \
    {                                                                            \
        const int k0_ = (kt_) * 64;                                              \
        _Pragma("unroll")                                                        \
        for (int v_ = 0; v_ < 4; ++v_) {                                         \
            int row_ = v_ * 64 + rsub;                                           \
            const __hip_bfloat16* ga_ = Wb + (size_t)(o0 + row_) * HH + k0_ + csw; \
            const __hip_bfloat16* gb_ = gT + (size_t)(n0 + row_) * HH + k0_ + csw; \
            char* dA_ = smem + (s_) * GSLOT + (v_ * 64 + wave * 8) * 128;        \
            char* dB_ = smem + 2 * GSLOT + (s_) * GSLOT + (v_ * 64 + wave * 8) * 128; \
            __builtin_amdgcn_global_load_lds(                                    \
                (const __attribute__((address_space(1))) void*)ga_,              \
                (__attribute__((address_space(3))) void*)dA_, 16, 0, 0);         \
            __builtin_amdgcn_global_load_lds(                                    \
                (const __attribute__((address_space(1))) void*)gb_,              \
                (__attribute__((address_space(3))) void*)dB_, 16, 0, 0);         \
        }                                                                        \
    }

#define COMPUTE_TILE(s_)                                                         \
    {                                                                            \
        const char* baseA = smem + (s_) * GSLOT;                                 \
        const char* baseB = smem + 2 * GSLOT + (s_) * GSLOT;                     \
        bf16x8 bfr[4][2];                                                        \
        _Pragma("unroll")                                                        \
        for (int nt = 0; nt < 4; ++nt)                                           \
            _Pragma("unroll")                                                    \
            for (int ks = 0; ks < 2; ++ks) {                                     \
                int rb = wn * 64 + nt * 16 + (lane & 15);                        \
                int c  = (ks * 32 + (lane >> 4) * 8) ^ ((rb & 7) << 3);          \
                bfr[nt][ks] = *(const bf16x8*)(baseB + rb * 128 + c * 2);        \
            }                                                                    \
        _Pragma("unroll")                                                        \
        for (int qq = 0; qq < 4; ++qq) {                                         \
            bf16x8 af[2][2];                                                     \
            _Pragma("unroll")                                                    \
            for (int mt = 0; mt < 2; ++mt)                                       \
                _Pragma("unroll")                                                \
                for (int ks = 0; ks < 2; ++ks) {                                 \
                    int ra = wm * 128 + (qq * 2 + mt) * 16 + (lane & 15);        \
                    int c  = (ks * 32 + (lane >> 4) * 8) ^ ((ra & 7) << 3);      \
                    af[mt][ks] = *(const bf16x8*)(baseA + ra * 128 + c * 2);     \
                }                                                                \
            __builtin_amdgcn_s_setprio(1);                                       \
            _Pragma("unroll")                                                    \
            for (int mt = 0; mt < 2; ++mt)                                       \
                _Pragma("unroll")                                                \
                for (int nt = 0; nt < 4; ++nt) {                                 \
                    acc[qq * 2 + mt][nt] = __builtin_amdgcn_mfma_f32_16x16x32_bf16( \
                        af[mt][0], bfr[nt][0], acc[qq * 2 + mt][nt], 0, 0, 0);   \
                    acc[qq * 2 + mt][nt] = __builtin_amdgcn_mfma_f32_16x16x32_bf16( \
                        af[mt][1], bfr[nt][1], acc[qq * 2 + mt][nt], 0, 0, 0);   \
                }                                                                \
            __builtin_amdgcn_s_setprio(0);                                       \
        }                                                                        \
    }

__global__ __launch_bounds__(512, 2) void out_gemm_256(
    const __hip_bfloat16* __restrict__ Wb,
    const __hip_bfloat16* __restrict__ gT,
    const float* __restrict__ bias,
    float* __restrict__ out)
{
    extern __shared__ char smem[];
    const int tid  = threadIdx.x;
    const int lane = tid & 63;
    const int wave = tid >> 6;
    const int wm = wave >> 2;
    const int wn = wave & 3;

    int wg  = blockIdx.x;
    int swz = (wg & 7) * 32 + (wg >> 3);
    const int o0 = (swz & 3) * 256;
    const int n0 = (swz >> 2) * 256;

    const int rsub = tid >> 3;
    const int csw  = ((tid & 7) ^ (rsub & 7)) << 3;

    f32x4 acc[8][4] = {};

    STAGE_TILE(0, 0)
    STAGE_TILE(1, 1)

    for (int t = 0; t < 15; ++t) {
        asm volatile("s_waitcnt vmcnt(8)" ::: "memory");
        __builtin_amdgcn_s_barrier();
        __builtin_amdgcn_sched_barrier(0);
        COMPUTE_TILE(t & 1)
        asm volatile("s_waitcnt lgkmcnt(0)" ::: "memory");
        __builtin_amdgcn_s_barrier();
        __builtin_amdgcn_sched_barrier(0);
        if (t < 14) STAGE_TILE(t + 2, t & 1)
    }
    asm volatile("s_waitcnt vmcnt(0)" ::: "memory");
    __builtin_amdgcn_s_barrier();
    __builtin_amdgcn_sched_barrier(0);
    COMPUTE_TILE(1)

    const int bb = n0 >> 11;
    #pragma unroll
    for (int m = 0; m < 8; ++m) {
        int o = o0 + wm * 128 + m * 16 + (lane >> 4) * 4;
        #pragma unroll
        for (int nt = 0; nt < 4; ++nt) {
            int n = n0 + wn * 64 + nt * 16 + (lane & 15);
            int l = n & 2047;
            #pragma unroll
            for (int r = 0; r < 4; ++r)
                out[((size_t)(bb * HH + o + r)) * LL + l] = acc[m][nt][r] + bias[o + r];
        }
    }
}

extern "C" void kernel_launch(void* const* d_in, const int* in_sizes, int n_in,
                              void* d_out, int out_size, void* d_ws, size_t ws_size,
                              hipStream_t stream) {
    const float* u          = (const float*)d_in[0];
    const float* log_dt     = (const float*)d_in[1];
    const float* log_w_real = (const float*)d_in[2];
    const float* w_imag     = (const float*)d_in[3];
    const float* C_re       = (const float*)d_in[4];
    const float* C_im       = (const float*)d_in[5];
    const float* Dp         = (const float*)d_in[6];
    const float* W          = (const float*)d_in[7];
    const float* bias       = (const float*)d_in[8];
    float* out = (float*)d_out;

    // d_out (64 MiB) = [AJ 16 MiB][AP 16 MiB][g 32 MiB]  (all consumed before
    // the final GEMM overwrites every byte of d_out)
    __hip_bfloat16* AJ_g = (__hip_bfloat16*)d_out;
    __hip_bfloat16* AP_g = (__hip_bfloat16*)((char*)d_out + 16777216);
    __hip_bfloat16* g    = (__hip_bfloat16*)((char*)d_out + 33554432);
    // ws: gT 33.5MB | Wb 2MB | misc 1MB
    __hip_bfloat16* gT     = (__hip_bfloat16*)d_ws;
    __hip_bfloat16* Wb     = (__hip_bfloat16*)((char*)d_ws + 33554432);
    float*          misc_g = (float*)((char*)d_ws + 35651584);

    hipFuncSetAttribute((const void*)ssm_mfma,
                        hipFuncAttributeMaxDynamicSharedMemorySize, S_TOT);
    hipFuncSetAttribute((const void*)out_gemm_256,
                        hipFuncAttributeMaxDynamicSharedMemorySize, 131072);

    aux_tables<<<dim3(HH), 256, 0, stream>>>(log_dt, log_w_real, w_imag,
                                             C_re, C_im, W, AJ_g, AP_g, misc_g, Wb);
    ssm_mfma<<<dim3(HH), 512, S_TOT, stream>>>(u, AJ_g, AP_g, misc_g, Dp, g);
    transpose_g<<<dim3(HH / 64, LL / 64, BB), 256, 0, stream>>>(g, gT);
    out_gemm_256<<<dim3(256), 512, 131072, stream>>>(Wb, gT, bias, out);
}

// Round 11
// 101.025 us; speedup vs baseline: 1.1314x; 1.0350x over previous
//
#include <hip/hip_runtime.h>
#include <hip/hip_bf16.h>

#define HH 1024
#define LL 2048
#define BB 8
#define NN2 32     // complex modes
#define CT 128     // chunk size
#define NCH 16     // LL / CT

typedef short bf16x8 __attribute__((ext_vector_type(8)));
typedef float f32x4  __attribute__((ext_vector_type(4)));

static __device__ __forceinline__ unsigned short bfbits(float x) {
    __hip_bfloat16 h = __float2bfloat16(x);
    return *(unsigned short*)&h;
}
static __device__ __forceinline__ float f_from_bits(unsigned short b) {
    __hip_bfloat16 h; *(unsigned short*)&h = b; return __bfloat162float(h);
}
// exp(dA * p), native ops, explicit range reduction.
static __device__ __forceinline__ float2 cexp_n(float2 dA, float p) {
    float mag = __expf(dA.x * p);
    float rev = dA.y * p * 0.15915494309f;
    rev -= floorf(rev);
    float ang = rev * 6.28318530718f;
    return make_float2(mag * __cosf(ang), mag * __sinf(ang));
}

#define SWZ(off, row) ((off) ^ (((row) & 7) << 4))

// ---------------------------------------------------------------------------
// Kernel 0: per-h tables -> global, PRE-SWIZZLED for global_load_lds staging.
// AJ_g[h]: 16KB  rows 2n/2n+1 (re/im), AJ[.][j] = a^(127-j)   (64x128 bf16)
// AP_g[h]: 16KB  AP[tt][2n]=2Re a^(tt+1), [2n+1]=-2Im         (128x64 bf16)
// misc_g[h]: 256 floats = kt[128] | Cn interleaved[64] | a^128 interleaved[64]
// ALSO converts W row h -> bf16 (merged conv_w).
// ---------------------------------------------------------------------------
__global__ __launch_bounds__(256) void aux_tables(
    const float* __restrict__ log_dt, const float* __restrict__ log_w_real,
    const float* __restrict__ w_imag, const float* __restrict__ C_re,
    const float* __restrict__ C_im, const float* __restrict__ W,
    __hip_bfloat16* __restrict__ AJ_g, __hip_bfloat16* __restrict__ AP_g,
    float* __restrict__ misc_g, __hip_bfloat16* __restrict__ Wb)
{
    __shared__ float2 dtA_s[NN2];
    __shared__ float2 Cn_s[NN2];
    const int tid = threadIdx.x;
    const int h = blockIdx.x;

    {   // merged conv_w: convert W row h
        float4 v = ((const float4*)(W + (size_t)h * HH))[tid];
        ushort4 o;
        o.x = bfbits(v.x); o.y = bfbits(v.y); o.z = bfbits(v.z); o.w = bfbits(v.w);
        ((ushort4*)(Wb + (size_t)h * HH))[tid] = o;
    }

    if (tid < NN2) {
        int n = tid;
        float dt = expf(log_dt[h]);
        float wr = -expf(log_w_real[n]);
        float wi = w_imag[n];
        float dar = wr * dt, dai = wi * dt;
        dtA_s[n] = make_float2(dar, dai);
        float er = expf(dar);
        float sn, cs; sincosf(dai, &sn, &cs);
        float exr = er * cs - 1.0f, exi = er * sn;
        float den = wr * wr + wi * wi;
        float fr = (exr * wr + exi * wi) / den;
        float fi = (exi * wr - exr * wi) / den;
        float cre = C_re[h * NN2 + n], cim = C_im[h * NN2 + n];
        float2 Cv = make_float2(cre * fr - cim * fi, cre * fi + cim * fr);
        Cn_s[n] = Cv;
        misc_g[h * 256 + 128 + 2 * n]     = Cv.x;
        misc_g[h * 256 + 128 + 2 * n + 1] = Cv.y;
        float magA = expf(dar * 128.0f);
        float snA, csA; sincosf(dai * 128.0f, &snA, &csA);
        misc_g[h * 256 + 192 + 2 * n]     = magA * csA;
        misc_g[h * 256 + 192 + 2 * n + 1] = magA * snA;
    }
    __syncthreads();

    char* ajb = (char*)AJ_g + (size_t)h * 16384;
    #pragma unroll
    for (int q = 0; q < 2; ++q) {
        int task = q * 256 + tid;              // 512 tasks: (n, j0 block of 8)
        int n = task >> 4, j0 = (task & 15) * 8;
        float2 dA = dtA_s[n];
        unsigned rw[4], iw[4];
        #pragma unroll
        for (int i2 = 0; i2 < 4; ++i2) {
            float2 a0 = cexp_n(dA, (float)(127 - j0 - 2 * i2));
            float2 a1 = cexp_n(dA, (float)(127 - j0 - 2 * i2 - 1));
            rw[i2] = (unsigned)bfbits(a0.x) | ((unsigned)bfbits(a1.x) << 16);
            iw[i2] = (unsigned)bfbits(a0.y) | ((unsigned)bfbits(a1.y) << 16);
        }
        int r0 = 2 * n, r1 = 2 * n + 1;
        *(uint4*)(ajb + SWZ(r0 * 256 + j0 * 2, r0)) = make_uint4(rw[0], rw[1], rw[2], rw[3]);
        *(uint4*)(ajb + SWZ(r1 * 256 + j0 * 2, r1)) = make_uint4(iw[0], iw[1], iw[2], iw[3]);
    }

    char* apb = (char*)AP_g + (size_t)h * 16384;
    #pragma unroll
    for (int q = 0; q < 2; ++q) {
        int task = q * 256 + tid;              // 512 tasks: (ttr, n0 block of 8)
        int ttr = task >> 2, n0 = (task & 3) * 8;
        unsigned w[8];
        #pragma unroll
        for (int i = 0; i < 8; ++i) {
            float2 a = cexp_n(dtA_s[n0 + i], (float)(ttr + 1));
            w[i] = (unsigned)bfbits(2.0f * a.x) | ((unsigned)bfbits(-2.0f * a.y) << 16);
        }
        *(uint4*)(apb + SWZ(ttr * 128 + n0 * 4, ttr))      = make_uint4(w[0], w[1], w[2], w[3]);
        *(uint4*)(apb + SWZ(ttr * 128 + n0 * 4 + 16, ttr)) = make_uint4(w[4], w[5], w[6], w[7]);
    }

    {   // kt[t] = 2 Re sum_n Cn a^t : 2 threads per tap
        int t = tid >> 1, nb = (tid & 1) * 16;
        float s = 0.f;
        #pragma unroll
        for (int i = 0; i < 16; ++i) {
            int n = nb + i;
            float2 a = cexp_n(dtA_s[n], (float)t);
            float2 C = Cn_s[n];
            s += C.x * a.x - C.y * a.y;
        }
        s += __shfl_xor(s, 1);
        if ((tid & 1) == 0) misc_g[h * 256 + t] = 2.0f * s;
    }
}

// ---------------- ssm LDS pool offsets (bytes), 4-batch split ----------------
#define S_U    0        // ushort U[64][128] swz (16384)
#define S_UN   16384    // 16KB union: AJ[64][128] -> AP[128][64]
#define S_P    32768    // ushort P/CS[64][64] swz (8192)
#define S_KT   40960    // kt[128] f32 | Cn f2[32] | A128 f2[32]  (1024)
#define S_KTP  41984    // ktp8: 8 copies x 264 bf16, stride 528B (4224)
#define S_TOT  46208    // 45.1 KB -> 3 blocks/CU

// ---------------------------------------------------------------------------
// Kernel 1: one block per (h, batch-half). 4 batches. 512 thr, 3 blocks/CU.
// R10 structure: ktp8 Toeplitz conv (no K build), early-AP staging, 4 barriers.
// ---------------------------------------------------------------------------
__global__ __launch_bounds__(512, 6) void ssm_mfma(
    const float* __restrict__ u,
    const __hip_bfloat16* __restrict__ AJ_g,
    const __hip_bfloat16* __restrict__ AP_g,
    const float* __restrict__ misc_g,
    const float* __restrict__ Dp, __hip_bfloat16* __restrict__ g_out)
{
    extern __shared__ char smem[];
    float*  kt   = (float*)(smem + S_KT);
    float2* CnL  = (float2*)(smem + S_KT + 512);
    float2* A128 = (float2*)(smem + S_KT + 768);

    const int tid  = threadIdx.x;
    const int lane = tid & 63;
    const int wave = tid >> 6;
    const int wm   = wave >> 2;     // 0..1 : 32 bc-rows each
    const int wn   = wave & 3;      // 0..3 : col groups
    const int h    = blockIdx.x;
    const int bh   = blockIdx.y;    // batches bh*4 .. bh*4+3

    // ---- issue table staging (AJ 16KB -> S_UN, misc 1KB -> S_KT) ----------
    {
        const char* ajs = (const char*)AJ_g + (size_t)h * 16384;
        __builtin_amdgcn_global_load_lds(
            (const __attribute__((address_space(1))) void*)(ajs + tid * 16),
            (__attribute__((address_space(3))) void*)(smem + S_UN + wave * 1024), 16, 0, 0);
        __builtin_amdgcn_global_load_lds(
            (const __attribute__((address_space(1))) void*)(ajs + 8192 + tid * 16),
            (__attribute__((address_space(3))) void*)(smem + S_UN + 8192 + wave * 1024), 16, 0, 0);
        if (tid < 64) {
            const char* ms = (const char*)misc_g + (size_t)h * 1024;
            __builtin_amdgcn_global_load_lds(
                (const __attribute__((address_space(1))) void*)(ms + tid * 16),
                (__attribute__((address_space(3))) void*)(smem + S_KT), 16, 0, 0);
        }
    }

    // ---- u load (4 batches) + bf16 convert -> U LDS -----------------------
    float4 ureg[4];
    #pragma unroll
    for (int q = 0; q < 4; ++q) {
        int b = bh * 4 + q;
        ureg[q] = *(const float4*)(u + ((size_t)(b * HH + h)) * LL + tid * 4);
    }
    #pragma unroll
    for (int q = 0; q < 4; ++q) {
        int row = q * 16 + (tid >> 5);          // bc row (4 batches x 16 chunks)
        int j   = (tid & 31) * 4;
        ushort4 o;
        o.x = bfbits(ureg[q].x); o.y = bfbits(ureg[q].y);
        o.z = bfbits(ureg[q].z); o.w = bfbits(ureg[q].w);
        *(ushort4*)(smem + SWZ(S_U + row * 256 + j * 2, row)) = o;
    }
    asm volatile("s_waitcnt vmcnt(0)" ::: "memory");
    __syncthreads();                                         // [1] AJ/misc/U ready

    // ---- build ktp8 (shift-replicated reversed kt, bf16) -------------------
    {
        int s = wave;            // 8 waves = 8 copies
        int i0 = lane * 4;
        ushort4 o;
        #pragma unroll
        for (int k = 0; k < 4; ++k) {
            int src = 127 - s - (i0 + k);
            ((unsigned short*)&o)[k] = (src >= 0) ? bfbits(kt[src]) : (unsigned short)0;
        }
        *(ushort4*)(smem + S_KTP + s * 528 + i0 * 2) = o;
        if (lane < 2) {
            *(ushort4*)(smem + S_KTP + s * 528 + 512 + lane * 8) = make_ushort4(0, 0, 0, 0);
        }
    }

    // ---- ph1: partials GEMM P[bc 64][n' 64] = U x AJ, K=128 ---------------
    f32x4 accP[2] = {};
    #pragma unroll
    for (int ks = 0; ks < 4; ++ks) {
        int kf = ks * 32 + (lane >> 4) * 8;
        bf16x8 a0, a1, b0;
        {
            int r = wm * 32 + (lane & 15);
            a0 = *(bf16x8*)(smem + SWZ(S_U + r * 256 + kf * 2, r));
            int r2 = r + 16;
            a1 = *(bf16x8*)(smem + SWZ(S_U + r2 * 256 + kf * 2, r2));
        }
        {
            int r = wn * 16 + (lane & 15);
            b0 = *(bf16x8*)(smem + SWZ(S_UN + r * 256 + kf * 2, r));
        }
        accP[0] = __builtin_amdgcn_mfma_f32_16x16x32_bf16(a0, b0, accP[0], 0, 0, 0);
        accP[1] = __builtin_amdgcn_mfma_f32_16x16x32_bf16(a1, b0, accP[1], 0, 0, 0);
    }
    #pragma unroll
    for (int mt = 0; mt < 2; ++mt)
        #pragma unroll
        for (int r = 0; r < 4; ++r) {
            int row = wm * 32 + mt * 16 + (lane >> 4) * 4 + r;
            int col = wn * 16 + (lane & 15);
            *(unsigned short*)(smem + SWZ(S_P + row * 128 + col * 2, row)) =
                bfbits(accP[mt][r]);
        }
    __syncthreads();                            // [2] AJ+ktp8 ready, P stored

    // ---- issue AP staging EARLY into freed S_UN (hides under scan+conv) ----
    {
        const char* aps = (const char*)AP_g + (size_t)h * 16384;
        __builtin_amdgcn_global_load_lds(
            (const __attribute__((address_space(1))) void*)(aps + tid * 16),
            (__attribute__((address_space(3))) void*)(smem + S_UN + wave * 1024), 16, 0, 0);
        __builtin_amdgcn_global_load_lds(
            (const __attribute__((address_space(1))) void*)(aps + 8192 + tid * 16),
            (__attribute__((address_space(3))) void*)(smem + S_UN + 8192 + wave * 1024), 16, 0, 0);
    }

    // ---- scan (tid<128: 4 batches x 32 modes), batched LDS reads -----------
    if (tid < 128) {
        int b = tid >> 5, n = tid & 31;
        float2 C = CnL[n];
        float2 A = A128[n];
        // independent reads first (pipelined), then serial recurrence, then writes
        unsigned int pv[NCH];
        int offs[NCH];
        #pragma unroll
        for (int c = 0; c < NCH; ++c) {
            int row = b * 16 + c;
            offs[c] = SWZ(S_P + row * 128 + n * 4, row);
            pv[c] = *(unsigned int*)(smem + offs[c]);
        }
        float sr = 0.f, si = 0.f;
        #pragma unroll
        for (int c = 0; c < NCH; ++c) {
            float pr = f_from_bits((unsigned short)(pv[c] & 0xffff));
            float pi = f_from_bits((unsigned short)(pv[c] >> 16));
            float csr = C.x * sr - C.y * si;
            float csi = C.x * si + C.y * sr;
            *(unsigned int*)(smem + offs[c]) =
                (unsigned)bfbits(csr) | ((unsigned)bfbits(csi) << 16);
            float nsr = A.x * sr - A.y * si + pr;
            float nsi = A.x * si + A.y * sr + pi;
            sr = nsr; si = nsi;
        }
    }

    // ---- conv GEMM (full K=128, Toeplitz B from ktp8) ----------------------
    f32x4 acc[2][2] = {};
    #pragma unroll
    for (int ks = 0; ks < 4; ++ks) {
        int kf = ks * 32 + (lane >> 4) * 8;
        bf16x8 a0, a1, bv[2];
        {
            int r = wm * 32 + (lane & 15);
            a0 = *(bf16x8*)(smem + SWZ(S_U + r * 256 + kf * 2, r));
            int r2 = r + 16;
            a1 = *(bf16x8*)(smem + SWZ(S_U + r2 * 256 + kf * 2, r2));
        }
        #pragma unroll
        for (int nt = 0; nt < 2; ++nt) {
            int ttr = wn * 32 + nt * 16 + (lane & 15);
            int s   = (127 - ttr) & 7;
            int gq  = (127 - ttr + kf) >> 3;
            bv[nt] = *(bf16x8*)(smem + S_KTP + s * 528 + gq * 16);
        }
        #pragma unroll
        for (int nt = 0; nt < 2; ++nt) {
            acc[0][nt] = __builtin_amdgcn_mfma_f32_16x16x32_bf16(a0, bv[nt], acc[0][nt], 0, 0, 0);
            acc[1][nt] = __builtin_amdgcn_mfma_f32_16x16x32_bf16(a1, bv[nt], acc[1][nt], 0, 0, 0);
        }
    }
    asm volatile("s_waitcnt vmcnt(0)" ::: "memory");         // AP landed
    __syncthreads();                                         // [3] CS + AP ready

    // ---- state GEMM (A = CS in S_P, B = AP in S_UN) ------------------------
    #pragma unroll
    for (int ks = 0; ks < 2; ++ks) {
        int kf = ks * 32 + (lane >> 4) * 8;
        bf16x8 a0, a1, bv[2];
        {
            int r = wm * 32 + (lane & 15);
            a0 = *(bf16x8*)(smem + SWZ(S_P + r * 128 + kf * 2, r));
            int r2 = r + 16;
            a1 = *(bf16x8*)(smem + SWZ(S_P + r2 * 128 + kf * 2, r2));
        }
        #pragma unroll
        for (int nt = 0; nt < 2; ++nt) {
            int ttr = wn * 32 + nt * 16 + (lane & 15);
            bv[nt] = *(bf16x8*)(smem + SWZ(S_UN + ttr * 128 + kf * 2, ttr));
        }
        #pragma unroll
        for (int nt = 0; nt < 2; ++nt) {
            acc[0][nt] = __builtin_amdgcn_mfma_f32_16x16x32_bf16(a0, bv[nt], acc[0][nt], 0, 0, 0);
            acc[1][nt] = __builtin_amdgcn_mfma_f32_16x16x32_bf16(a1, bv[nt], acc[1][nt], 0, 0, 0);
        }
    }

    // ---- epilogue: y = acc + D*u, GELU -> LDS -> packed stores ------------
    const float Dv = Dp[h];
    #pragma unroll
    for (int mt = 0; mt < 2; ++mt)
        #pragma unroll
        for (int nt = 0; nt < 2; ++nt)
            #pragma unroll
            for (int r = 0; r < 4; ++r) {
                int row = wm * 32 + mt * 16 + (lane >> 4) * 4 + r;
                int ttr = wn * 32 + nt * 16 + (lane & 15);
                int off = SWZ(S_U + row * 256 + ttr * 2, row);
                float uv = f_from_bits(*(unsigned short*)(smem + off));
                float y = acc[mt][nt][r] + Dv * uv;
                float z = 0.7978845608f * (y + 0.044715f * y * y * y);
                float e = __expf(2.0f * z);
                float th = 1.0f - 2.0f / (e + 1.0f);
                float gel = 0.5f * y * (1.0f + th);
                *(unsigned short*)(smem + off) = bfbits(gel);
            }
    __syncthreads();                                         // [4]
    #pragma unroll
    for (int q = 0; q < 2; ++q) {
        int flat = q * 512 + tid;               // 1024 uint4 tiles
        int row = flat >> 4, c16 = flat & 15;
        uint4 v = *(uint4*)(smem + SWZ(S_U + row * 256 + c16 * 16, row));
        int b = bh * 4 + (row >> 4), c = row & 15;
        *(uint4*)(g_out + ((size_t)(b * HH + h)) * LL + c * CT + c16 * 8) = v;
    }
}

// ---------------------------------------------------------------------------
// Kernel 3: transpose g (B,H,L) bf16 -> gT (B,L,H) bf16
// ---------------------------------------------------------------------------
__global__ __launch_bounds__(256) void transpose_g(
    const __hip_bfloat16* __restrict__ g, __hip_bfloat16* __restrict__ gT)
{
    __shared__ __hip_bfloat16 t[64][66];
    const int tid = threadIdx.x;
    const int b  = blockIdx.z;
    const int h0 = blockIdx.x * 64;
    const int l0 = blockIdx.y * 64;

    #pragma unroll
    for (int q = 0; q < 2; ++q) {
        int idx = tid + q * 256;
        int r = idx >> 3, c8 = (idx & 7) * 8;
        uint4 v = *(const uint4*)(g + ((size_t)(b * HH + h0 + r)) * LL + l0 + c8);
        unsigned int* dst = (unsigned int*)&t[r][c8];
        dst[0] = v.x; dst[1] = v.y; dst[2] = v.z; dst[3] = v.w;
    }
    __syncthreads();
    #pragma unroll
    for (int q = 0; q < 2; ++q) {
        int idx = tid + q * 256;
        int r = idx >> 3, c8 = (idx & 7) * 8;
        unsigned short tmp[8];
        #pragma unroll
        for (int j = 0; j < 8; ++j) tmp[j] = *(unsigned short*)&t[c8 + j][r];
        uint4 o;
        o.x = (unsigned)tmp[0] | ((unsigned)tmp[1] << 16);
        o.y = (unsigned)tmp[2] | ((unsigned)tmp[3] << 16);
        o.z = (unsigned)tmp[4] | ((unsigned)tmp[5] << 16);
        o.w = (unsigned)tmp[6] | ((unsigned)tmp[7] << 16);
        *(uint4*)(gT + ((size_t)(b * LL + l0 + r)) * HH + h0 + c8) = o;
    }
}

// ---------------------------------------------------------------------------
// Kernel 4: out = Wb x gT^T + bias (unchanged)
// ---------------------------------------------------------------------------
#define GSLOT 32768
#define STAGE_TILE(kt_, s_)                                                      \
    {                                                                            \
        const int k0_ = (kt_) * 64;                                              \
        _Pragma("unroll")                                                        \
        for (int v_ = 0; v_ < 4; ++v_) {                                         \
            int row_ = v_ * 64 + rsub;                                           \
            const __hip_bfloat16* ga_ = Wb + (size_t)(o0 + row_) * HH + k0_ + csw; \
            const __hip_bfloat16* gb_ = gT + (size_t)(n0 + row_) * HH + k0_ + csw; \
            char* dA_ = smem + (s_) * GSLOT + (v_ * 64 + wave * 8) * 128;        \
            char* dB_ = smem + 2 * GSLOT + (s_) * GSLOT + (v_ * 64 + wave * 8) * 128; \
            __builtin_amdgcn_global_load_lds(                                    \
                (const __attribute__((address_space(1))) void*)ga_,              \
                (__attribute__((address_space(3))) void*)dA_, 16, 0, 0);         \
            __builtin_amdgcn_global_load_lds(                                    \
                (const __attribute__((address_space(1))) void*)gb_,              \
                (__attribute__((address_space(3))) void*)dB_, 16, 0, 0);         \
        }                                                                        \
    }

#define COMPUTE_TILE(s_)                                                         \
    {                                                                            \
        const char* baseA = smem + (s_) * GSLOT;                                 \
        const char* baseB = smem + 2 * GSLOT + (s_) * GSLOT;                     \
        bf16x8 bfr[4][2];                                                        \
        _Pragma("unroll")                                                        \
        for (int nt = 0; nt < 4; ++nt)                                           \
            _Pragma("unroll")                                                    \
            for (int ks = 0; ks < 2; ++ks) {                                     \
                int rb = wn * 64 + nt * 16 + (lane & 15);                        \
                int c  = (ks * 32 + (lane >> 4) * 8) ^ ((rb & 7) << 3);          \
                bfr[nt][ks] = *(const bf16x8*)(baseB + rb * 128 + c * 2);        \
            }                                                                    \
        _Pragma("unroll")                                                        \
        for (int qq = 0; qq < 4; ++qq) {                                         \
            bf16x8 af[2][2];                                                     \
            _Pragma("unroll")                                                    \
            for (int mt = 0; mt < 2; ++mt)                                       \
                _Pragma("unroll")                                                \
                for (int ks = 0; ks < 2; ++ks) {                                 \
                    int ra = wm * 128 + (qq * 2 + mt) * 16 + (lane & 15);        \
                    int c  = (ks * 32 + (lane >> 4) * 8) ^ ((ra & 7) << 3);      \
                    af[mt][ks] = *(const bf16x8*)(baseA + ra * 128 + c * 2);     \
                }                                                                \
            __builtin_amdgcn_s_setprio(1);                                       \
            _Pragma("unroll")                                                    \
            for (int mt = 0; mt < 2; ++mt)                                       \
                _Pragma("unroll")                                                \
                for (int nt = 0; nt < 4; ++nt) {                                 \
                    acc[qq * 2 + mt][nt] = __builtin_amdgcn_mfma_f32_16x16x32_bf16( \
                        af[mt][0], bfr[nt][0], acc[qq * 2 + mt][nt], 0, 0, 0);   \
                    acc[qq * 2 + mt][nt] = __builtin_amdgcn_mfma_f32_16x16x32_bf16( \
                        af[mt][1], bfr[nt][1], acc[qq * 2 + mt][nt], 0, 0, 0);   \
                }                                                                \
            __builtin_amdgcn_s_setprio(0);                                       \
        }                                                                        \
    }

__global__ __launch_bounds__(512, 2) void out_gemm_256(
    const __hip_bfloat16* __restrict__ Wb,
    const __hip_bfloat16* __restrict__ gT,
    const float* __restrict__ bias,
    float* __restrict__ out)
{
    extern __shared__ char smem[];
    const int tid  = threadIdx.x;
    const int lane = tid & 63;
    const int wave = tid >> 6;
    const int wm = wave >> 2;
    const int wn = wave & 3;

    int wg  = blockIdx.x;
    int swz = (wg & 7) * 32 + (wg >> 3);
    const int o0 = (swz & 3) * 256;
    const int n0 = (swz >> 2) * 256;

    const int rsub = tid >> 3;
    const int csw  = ((tid & 7) ^ (rsub & 7)) << 3;

    f32x4 acc[8][4] = {};

    STAGE_TILE(0, 0)
    STAGE_TILE(1, 1)

    for (int t = 0; t < 15; ++t) {
        asm volatile("s_waitcnt vmcnt(8)" ::: "memory");
        __builtin_amdgcn_s_barrier();
        __builtin_amdgcn_sched_barrier(0);
        COMPUTE_TILE(t & 1)
        asm volatile("s_waitcnt lgkmcnt(0)" ::: "memory");
        __builtin_amdgcn_s_barrier();
        __builtin_amdgcn_sched_barrier(0);
        if (t < 14) STAGE_TILE(t + 2, t & 1)
    }
    asm volatile("s_waitcnt vmcnt(0)" ::: "memory");
    __builtin_amdgcn_s_barrier();
    __builtin_amdgcn_sched_barrier(0);
    COMPUTE_TILE(1)

    const int bb = n0 >> 11;
    #pragma unroll
    for (int m = 0; m < 8; ++m) {
        int o = o0 + wm * 128 + m * 16 + (lane >> 4) * 4;
        #pragma unroll
        for (int nt = 0; nt < 4; ++nt) {
            int n = n0 + wn * 64 + nt * 16 + (lane & 15);
            int l = n & 2047;
            #pragma unroll
            for (int r = 0; r < 4; ++r)
                out[((size_t)(bb * HH + o + r)) * LL + l] = acc[m][nt][r] + bias[o + r];
        }
    }
}

extern "C" void kernel_launch(void* const* d_in, const int* in_sizes, int n_in,
                              void* d_out, int out_size, void* d_ws, size_t ws_size,
                              hipStream_t stream) {
    const float* u          = (const float*)d_in[0];
    const float* log_dt     = (const float*)d_in[1];
    const float* log_w_real = (const float*)d_in[2];
    const float* w_imag     = (const float*)d_in[3];
    const float* C_re       = (const float*)d_in[4];
    const float* C_im       = (const float*)d_in[5];
    const float* Dp         = (const float*)d_in[6];
    const float* W          = (const float*)d_in[7];
    const float* bias       = (const float*)d_in[8];
    float* out = (float*)d_out;

    // d_out (64 MiB) = [AJ 16 MiB][AP 16 MiB][g 32 MiB]
    __hip_bfloat16* AJ_g = (__hip_bfloat16*)d_out;
    __hip_bfloat16* AP_g = (__hip_bfloat16*)((char*)d_out + 16777216);
    __hip_bfloat16* g    = (__hip_bfloat16*)((char*)d_out + 33554432);
    // ws: gT 33.5MB | Wb 2MB | misc 1MB
    __hip_bfloat16* gT     = (__hip_bfloat16*)d_ws;
    __hip_bfloat16* Wb     = (__hip_bfloat16*)((char*)d_ws + 33554432);
    float*          misc_g = (float*)((char*)d_ws + 35651584);

    hipFuncSetAttribute((const void*)ssm_mfma,
                        hipFuncAttributeMaxDynamicSharedMemorySize, S_TOT);
    hipFuncSetAttribute((const void*)out_gemm_256,
                        hipFuncAttributeMaxDynamicSharedMemorySize, 131072);

    aux_tables<<<dim3(HH), 256, 0, stream>>>(log_dt, log_w_real, w_imag,
                                             C_re, C_im, W, AJ_g, AP_g, misc_g, Wb);
    ssm_mfma<<<dim3(HH, 2), 512, S_TOT, stream>>>(u, AJ_g, AP_g, misc_g, Dp, g);
    transpose_g<<<dim3(HH / 64, LL / 64, BB), 256, 0, stream>>>(g, gT);
    out_gemm_256<<<dim3(256), 512, 131072, stream>>>(Wb, gT, bias, out);
}

// Round 14
// 100.925 us; speedup vs baseline: 1.1326x; 1.0010x over previous
//
#include <hip/hip_runtime.h>
#include <hip/hip_bf16.h>

#define HH 1024
#define LL 2048
#define BB 8
#define NN2 32     // complex modes
#define CT 128     // chunk size
#define NCH 16     // LL / CT

typedef short bf16x8 __attribute__((ext_vector_type(8)));
typedef float f32x4  __attribute__((ext_vector_type(4)));

static __device__ __forceinline__ unsigned short bfbits(float x) {
    __hip_bfloat16 h = __float2bfloat16(x);
    return *(unsigned short*)&h;
}
static __device__ __forceinline__ float f_from_bits(unsigned short b) {
    __hip_bfloat16 h; *(unsigned short*)&h = b; return __bfloat162float(h);
}
// exp(dA * p), native ops, explicit range reduction.
static __device__ __forceinline__ float2 cexp_n(float2 dA, float p) {
    float mag = __expf(dA.x * p);
    float rev = dA.y * p * 0.15915494309f;
    rev -= floorf(rev);
    float ang = rev * 6.28318530718f;
    return make_float2(mag * __cosf(ang), mag * __sinf(ang));
}

#define SWZ(off, row) ((off) ^ (((row) & 7) << 4))

// ---------------------------------------------------------------------------
// Kernel 0: per-h tables -> global, PRE-SWIZZLED for global_load_lds staging.
// ---------------------------------------------------------------------------
__global__ __launch_bounds__(256) void aux_tables(
    const float* __restrict__ log_dt, const float* __restrict__ log_w_real,
    const float* __restrict__ w_imag, const float* __restrict__ C_re,
    const float* __restrict__ C_im, const float* __restrict__ W,
    __hip_bfloat16* __restrict__ AJ_g, __hip_bfloat16* __restrict__ AP_g,
    float* __restrict__ misc_g, __hip_bfloat16* __restrict__ Wb)
{
    __shared__ float2 dtA_s[NN2];
    __shared__ float2 Cn_s[NN2];
    const int tid = threadIdx.x;
    const int h = blockIdx.x;

    {   // merged conv_w: convert W row h
        float4 v = ((const float4*)(W + (size_t)h * HH))[tid];
        ushort4 o;
        o.x = bfbits(v.x); o.y = bfbits(v.y); o.z = bfbits(v.z); o.w = bfbits(v.w);
        ((ushort4*)(Wb + (size_t)h * HH))[tid] = o;
    }

    if (tid < NN2) {
        int n = tid;
        float dt = expf(log_dt[h]);
        float wr = -expf(log_w_real[n]);
        float wi = w_imag[n];
        float dar = wr * dt, dai = wi * dt;
        dtA_s[n] = make_float2(dar, dai);
        float er = expf(dar);
        float sn, cs; sincosf(dai, &sn, &cs);
        float exr = er * cs - 1.0f, exi = er * sn;
        float den = wr * wr + wi * wi;
        float fr = (exr * wr + exi * wi) / den;
        float fi = (exi * wr - exr * wi) / den;
        float cre = C_re[h * NN2 + n], cim = C_im[h * NN2 + n];
        float2 Cv = make_float2(cre * fr - cim * fi, cre * fi + cim * fr);
        Cn_s[n] = Cv;
        misc_g[h * 256 + 128 + 2 * n]     = Cv.x;
        misc_g[h * 256 + 128 + 2 * n + 1] = Cv.y;
        float magA = expf(dar * 128.0f);
        float snA, csA; sincosf(dai * 128.0f, &snA, &csA);
        misc_g[h * 256 + 192 + 2 * n]     = magA * csA;
        misc_g[h * 256 + 192 + 2 * n + 1] = magA * snA;
    }
    __syncthreads();

    char* ajb = (char*)AJ_g + (size_t)h * 16384;
    #pragma unroll
    for (int q = 0; q < 2; ++q) {
        int task = q * 256 + tid;              // 512 tasks: (n, j0 block of 8)
        int n = task >> 4, j0 = (task & 15) * 8;
        float2 dA = dtA_s[n];
        unsigned rw[4], iw[4];
        #pragma unroll
        for (int i2 = 0; i2 < 4; ++i2) {
            float2 a0 = cexp_n(dA, (float)(127 - j0 - 2 * i2));
            float2 a1 = cexp_n(dA, (float)(127 - j0 - 2 * i2 - 1));
            rw[i2] = (unsigned)bfbits(a0.x) | ((unsigned)bfbits(a1.x) << 16);
            iw[i2] = (unsigned)bfbits(a0.y) | ((unsigned)bfbits(a1.y) << 16);
        }
        int r0 = 2 * n, r1 = 2 * n + 1;
        *(uint4*)(ajb + SWZ(r0 * 256 + j0 * 2, r0)) = make_uint4(rw[0], rw[1], rw[2], rw[3]);
        *(uint4*)(ajb + SWZ(r1 * 256 + j0 * 2, r1)) = make_uint4(iw[0], iw[1], iw[2], iw[3]);
    }

    char* apb = (char*)AP_g + (size_t)h * 16384;
    #pragma unroll
    for (int q = 0; q < 2; ++q) {
        int task = q * 256 + tid;              // 512 tasks: (ttr, n0 block of 8)
        int ttr = task >> 2, n0 = (task & 3) * 8;
        unsigned w[8];
        #pragma unroll
        for (int i = 0; i < 8; ++i) {
            float2 a = cexp_n(dtA_s[n0 + i], (float)(ttr + 1));
            w[i] = (unsigned)bfbits(2.0f * a.x) | ((unsigned)bfbits(-2.0f * a.y) << 16);
        }
        *(uint4*)(apb + SWZ(ttr * 128 + n0 * 4, ttr))      = make_uint4(w[0], w[1], w[2], w[3]);
        *(uint4*)(apb + SWZ(ttr * 128 + n0 * 4 + 16, ttr)) = make_uint4(w[4], w[5], w[6], w[7]);
    }

    {   // kt[t] = 2 Re sum_n Cn a^t : 2 threads per tap
        int t = tid >> 1, nb = (tid & 1) * 16;
        float s = 0.f;
        #pragma unroll
        for (int i = 0; i < 16; ++i) {
            int n = nb + i;
            float2 a = cexp_n(dtA_s[n], (float)t);
            float2 C = Cn_s[n];
            s += C.x * a.x - C.y * a.y;
        }
        s += __shfl_xor(s, 1);
        if ((tid & 1) == 0) misc_g[h * 256 + t] = 2.0f * s;
    }
}

// ---------------- ssm LDS pool offsets (bytes), 4-batch split ----------------
#define S_U    0        // ushort U[64][128] swz (16384)
#define S_UN   16384    // 16KB union: AJ[64][128] -> AP[128][64]
#define S_P    32768    // ushort P/CS[64][64] swz (8192)
#define S_KT   40960    // kt[128] f32 | Cn f2[32] | A128 f2[32]  (1024)
#define S_KTP  41984    // ktp8: 8 copies x 264 bf16, stride 528B (4224)
#define S_TOT  46208    // 45.1 KB -> 3 blocks/CU

// ---------------------------------------------------------------------------
// Kernel 1: one block per (h, batch-half). 4 batches. (R11 verbatim)
// ---------------------------------------------------------------------------
__global__ __launch_bounds__(512, 6) void ssm_mfma(
    const float* __restrict__ u,
    const __hip_bfloat16* __restrict__ AJ_g,
    const __hip_bfloat16* __restrict__ AP_g,
    const float* __restrict__ misc_g,
    const float* __restrict__ Dp, __hip_bfloat16* __restrict__ g_out)
{
    extern __shared__ char smem[];
    float*  kt   = (float*)(smem + S_KT);
    float2* CnL  = (float2*)(smem + S_KT + 512);
    float2* A128 = (float2*)(smem + S_KT + 768);

    const int tid  = threadIdx.x;
    const int lane = tid & 63;
    const int wave = tid >> 6;
    const int wm   = wave >> 2;     // 0..1 : 32 bc-rows each
    const int wn   = wave & 3;      // 0..3 : col groups
    const int h    = blockIdx.x;
    const int bh   = blockIdx.y;    // batches bh*4 .. bh*4+3

    // ---- issue table staging (AJ 16KB -> S_UN, misc 1KB -> S_KT) ----------
    {
        const char* ajs = (const char*)AJ_g + (size_t)h * 16384;
        __builtin_amdgcn_global_load_lds(
            (const __attribute__((address_space(1))) void*)(ajs + tid * 16),
            (__attribute__((address_space(3))) void*)(smem + S_UN + wave * 1024), 16, 0, 0);
        __builtin_amdgcn_global_load_lds(
            (const __attribute__((address_space(1))) void*)(ajs + 8192 + tid * 16),
            (__attribute__((address_space(3))) void*)(smem + S_UN + 8192 + wave * 1024), 16, 0, 0);
        if (tid < 64) {
            const char* ms = (const char*)misc_g + (size_t)h * 1024;
            __builtin_amdgcn_global_load_lds(
                (const __attribute__((address_space(1))) void*)(ms + tid * 16),
                (__attribute__((address_space(3))) void*)(smem + S_KT), 16, 0, 0);
        }
    }

    // ---- u load (4 batches) + bf16 convert -> U LDS -----------------------
    float4 ureg[4];
    #pragma unroll
    for (int q = 0; q < 4; ++q) {
        int b = bh * 4 + q;
        ureg[q] = *(const float4*)(u + ((size_t)(b * HH + h)) * LL + tid * 4);
    }
    #pragma unroll
    for (int q = 0; q < 4; ++q) {
        int row = q * 16 + (tid >> 5);          // bc row (4 batches x 16 chunks)
        int j   = (tid & 31) * 4;
        ushort4 o;
        o.x = bfbits(ureg[q].x); o.y = bfbits(ureg[q].y);
        o.z = bfbits(ureg[q].z); o.w = bfbits(ureg[q].w);
        *(ushort4*)(smem + SWZ(S_U + row * 256 + j * 2, row)) = o;
    }
    asm volatile("s_waitcnt vmcnt(0)" ::: "memory");
    __syncthreads();                                         // [1] AJ/misc/U ready

    // ---- build ktp8 (shift-replicated reversed kt, bf16) -------------------
    {
        int s = wave;            // 8 waves = 8 copies
        int i0 = lane * 4;
        ushort4 o;
        #pragma unroll
        for (int k = 0; k < 4; ++k) {
            int src = 127 - s - (i0 + k);
            ((unsigned short*)&o)[k] = (src >= 0) ? bfbits(kt[src]) : (unsigned short)0;
        }
        *(ushort4*)(smem + S_KTP + s * 528 + i0 * 2) = o;
        if (lane < 2) {
            *(ushort4*)(smem + S_KTP + s * 528 + 512 + lane * 8) = make_ushort4(0, 0, 0, 0);
        }
    }

    // ---- ph1: partials GEMM P[bc 64][n' 64] = U x AJ, K=128 ---------------
    f32x4 accP[2] = {};
    #pragma unroll
    for (int ks = 0; ks < 4; ++ks) {
        int kf = ks * 32 + (lane >> 4) * 8;
        bf16x8 a0, a1, b0;
        {
            int r = wm * 32 + (lane & 15);
            a0 = *(bf16x8*)(smem + SWZ(S_U + r * 256 + kf * 2, r));
            int r2 = r + 16;
            a1 = *(bf16x8*)(smem + SWZ(S_U + r2 * 256 + kf * 2, r2));
        }
        {
            int r = wn * 16 + (lane & 15);
            b0 = *(bf16x8*)(smem + SWZ(S_UN + r * 256 + kf * 2, r));
        }
        accP[0] = __builtin_amdgcn_mfma_f32_16x16x32_bf16(a0, b0, accP[0], 0, 0, 0);
        accP[1] = __builtin_amdgcn_mfma_f32_16x16x32_bf16(a1, b0, accP[1], 0, 0, 0);
    }
    #pragma unroll
    for (int mt = 0; mt < 2; ++mt)
        #pragma unroll
        for (int r = 0; r < 4; ++r) {
            int row = wm * 32 + mt * 16 + (lane >> 4) * 4 + r;
            int col = wn * 16 + (lane & 15);
            *(unsigned short*)(smem + SWZ(S_P + row * 128 + col * 2, row)) =
                bfbits(accP[mt][r]);
        }
    __syncthreads();                            // [2] AJ+ktp8 ready, P stored

    // ---- issue AP staging EARLY into freed S_UN (hides under scan+conv) ----
    {
        const char* aps = (const char*)AP_g + (size_t)h * 16384;
        __builtin_amdgcn_global_load_lds(
            (const __attribute__((address_space(1))) void*)(aps + tid * 16),
            (__attribute__((address_space(3))) void*)(smem + S_UN + wave * 1024), 16, 0, 0);
        __builtin_amdgcn_global_load_lds(
            (const __attribute__((address_space(1))) void*)(aps + 8192 + tid * 16),
            (__attribute__((address_space(3))) void*)(smem + S_UN + 8192 + wave * 1024), 16, 0, 0);
    }

    // ---- scan (tid<128: 4 batches x 32 modes), batched LDS reads -----------
    if (tid < 128) {
        int b = tid >> 5, n = tid & 31;
        float2 C = CnL[n];
        float2 A = A128[n];
        unsigned int pv[NCH];
        int offs[NCH];
        #pragma unroll
        for (int c = 0; c < NCH; ++c) {
            int row = b * 16 + c;
            offs[c] = SWZ(S_P + row * 128 + n * 4, row);
            pv[c] = *(unsigned int*)(smem + offs[c]);
        }
        float sr = 0.f, si = 0.f;
        #pragma unroll
        for (int c = 0; c < NCH; ++c) {
            float pr = f_from_bits((unsigned short)(pv[c] & 0xffff));
            float pi = f_from_bits((unsigned short)(pv[c] >> 16));
            float csr = C.x * sr - C.y * si;
            float csi = C.x * si + C.y * sr;
            *(unsigned int*)(smem + offs[c]) =
                (unsigned)bfbits(csr) | ((unsigned)bfbits(csi) << 16);
            float nsr = A.x * sr - A.y * si + pr;
            float nsi = A.x * si + A.y * sr + pi;
            sr = nsr; si = nsi;
        }
    }

    // ---- conv GEMM (full K=128, Toeplitz B from ktp8) ----------------------
    f32x4 acc[2][2] = {};
    #pragma unroll
    for (int ks = 0; ks < 4; ++ks) {
        int kf = ks * 32 + (lane >> 4) * 8;
        bf16x8 a0, a1, bv[2];
        {
            int r = wm * 32 + (lane & 15);
            a0 = *(bf16x8*)(smem + SWZ(S_U + r * 256 + kf * 2, r));
            int r2 = r + 16;
            a1 = *(bf16x8*)(smem + SWZ(S_U + r2 * 256 + kf * 2, r2));
        }
        #pragma unroll
        for (int nt = 0; nt < 2; ++nt) {
            int ttr = wn * 32 + nt * 16 + (lane & 15);
            int s   = (127 - ttr) & 7;
            int gq  = (127 - ttr + kf) >> 3;
            bv[nt] = *(bf16x8*)(smem + S_KTP + s * 528 + gq * 16);
        }
        #pragma unroll
        for (int nt = 0; nt < 2; ++nt) {
            acc[0][nt] = __builtin_amdgcn_mfma_f32_16x16x32_bf16(a0, bv[nt], acc[0][nt], 0, 0, 0);
            acc[1][nt] = __builtin_amdgcn_mfma_f32_16x16x32_bf16(a1, bv[nt], acc[1][nt], 0, 0, 0);
        }
    }
    asm volatile("s_waitcnt vmcnt(0)" ::: "memory");         // AP landed
    __syncthreads();                                         // [3] CS + AP ready

    // ---- state GEMM (A = CS in S_P, B = AP in S_UN) ------------------------
    #pragma unroll
    for (int ks = 0; ks < 2; ++ks) {
        int kf = ks * 32 + (lane >> 4) * 8;
        bf16x8 a0, a1, bv[2];
        {
            int r = wm * 32 + (lane & 15);
            a0 = *(bf16x8*)(smem + SWZ(S_P + r * 128 + kf * 2, r));
            int r2 = r + 16;
            a1 = *(bf16x8*)(smem + SWZ(S_P + r2 * 128 + kf * 2, r2));
        }
        #pragma unroll
        for (int nt = 0; nt < 2; ++nt) {
            int ttr = wn * 32 + nt * 16 + (lane & 15);
            bv[nt] = *(bf16x8*)(smem + SWZ(S_UN + ttr * 128 + kf * 2, ttr));
        }
        #pragma unroll
        for (int nt = 0; nt < 2; ++nt) {
            acc[0][nt] = __builtin_amdgcn_mfma_f32_16x16x32_bf16(a0, bv[nt], acc[0][nt], 0, 0, 0);
            acc[1][nt] = __builtin_amdgcn_mfma_f32_16x16x32_bf16(a1, bv[nt], acc[1][nt], 0, 0, 0);
        }
    }

    // ---- epilogue: y = acc + D*u, GELU -> LDS -> packed stores ------------
    const float Dv = Dp[h];
    #pragma unroll
    for (int mt = 0; mt < 2; ++mt)
        #pragma unroll
        for (int nt = 0; nt < 2; ++nt)
            #pragma unroll
            for (int r = 0; r < 4; ++r) {
                int row = wm * 32 + mt * 16 + (lane >> 4) * 4 + r;
                int ttr = wn * 32 + nt * 16 + (lane & 15);
                int off = SWZ(S_U + row * 256 + ttr * 2, row);
                float uv = f_from_bits(*(unsigned short*)(smem + off));
                float y = acc[mt][nt][r] + Dv * uv;
                float z = 0.7978845608f * (y + 0.044715f * y * y * y);
                float e = __expf(2.0f * z);
                float th = 1.0f - 2.0f / (e + 1.0f);
                float gel = 0.5f * y * (1.0f + th);
                *(unsigned short*)(smem + off) = bfbits(gel);
            }
    __syncthreads();                                         // [4]
    #pragma unroll
    for (int q = 0; q < 2; ++q) {
        int flat = q * 512 + tid;               // 1024 uint4 tiles
        int row = flat >> 4, c16 = flat & 15;
        uint4 v = *(uint4*)(smem + SWZ(S_U + row * 256 + c16 * 16, row));
        int b = bh * 4 + (row >> 4), c = row & 15;
        *(uint4*)(g_out + ((size_t)(b * HH + h)) * LL + c * CT + c16 * 8) = v;
    }
}

// ---------------------------------------------------------------------------
// Kernel 3: transpose g (B,H,L) bf16 -> gT (B,L,H) bf16  (R11 verbatim)
// ---------------------------------------------------------------------------
__global__ __launch_bounds__(256) void transpose_g(
    const __hip_bfloat16* __restrict__ g, __hip_bfloat16* __restrict__ gT)
{
    __shared__ __hip_bfloat16 t[64][66];
    const int tid = threadIdx.x;
    const int b  = blockIdx.z;
    const int h0 = blockIdx.x * 64;
    const int l0 = blockIdx.y * 64;

    #pragma unroll
    for (int q = 0; q < 2; ++q) {
        int idx = tid + q * 256;
        int r = idx >> 3, c8 = (idx & 7) * 8;
        uint4 v = *(const uint4*)(g + ((size_t)(b * HH + h0 + r)) * LL + l0 + c8);
        unsigned int* dst = (unsigned int*)&t[r][c8];
        dst[0] = v.x; dst[1] = v.y; dst[2] = v.z; dst[3] = v.w;
    }
    __syncthreads();
    #pragma unroll
    for (int q = 0; q < 2; ++q) {
        int idx = tid + q * 256;
        int r = idx >> 3, c8 = (idx & 7) * 8;
        unsigned short tmp[8];
        #pragma unroll
        for (int j = 0; j < 8; ++j) tmp[j] = *(unsigned short*)&t[c8 + j][r];
        uint4 o;
        o.x = (unsigned)tmp[0] | ((unsigned)tmp[1] << 16);
        o.y = (unsigned)tmp[2] | ((unsigned)tmp[3] << 16);
        o.z = (unsigned)tmp[4] | ((unsigned)tmp[5] << 16);
        o.w = (unsigned)tmp[6] | ((unsigned)tmp[7] << 16);
        *(uint4*)(gT + ((size_t)(b * LL + l0 + r)) * HH + h0 + c8) = o;
    }
}

// ---------------------------------------------------------------------------
// Kernel 4: out = Wb x gT^T + bias.  128x128 tile, BK=64, 4 waves (2Mx2N),
// 64KB LDS dbuf -> 2 blocks/CU, counted vmcnt (same skeleton as 256² version).
// ---------------------------------------------------------------------------
#define GSLOT 16384                 // bytes per operand slot (128x64 bf16)
#define STAGE_TILE(kt_, s_)                                                      \
    {                                                                            \
        const int k0_ = (kt_) * 64;                                              \
        _Pragma("unroll")                                                        \
        for (int v_ = 0; v_ < 4; ++v_) {                                         \
            int row_ = v_ * 32 + rsub;                                           \
            const __hip_bfloat16* ga_ = Wb + (size_t)(o0 + row_) * HH + k0_ + csw; \
            const __hip_bfloat16* gb_ = gT + (size_t)(n0 + row_) * HH + k0_ + csw; \
            char* dA_ = smem + (s_) * GSLOT + (v_ * 32 + wave * 8) * 128;        \
            char* dB_ = smem + 2 * GSLOT + (s_) * GSLOT + (v_ * 32 + wave * 8) * 128; \
            __builtin_amdgcn_global_load_lds(                                    \
                (const __attribute__((address_space(1))) void*)ga_,              \
                (__attribute__((address_space(3))) void*)dA_, 16, 0, 0);         \
            __builtin_amdgcn_global_load_lds(                                    \
                (const __attribute__((address_space(1))) void*)gb_,              \
                (__attribute__((address_space(3))) void*)dB_, 16, 0, 0);         \
        }                                                                        \
    }

#define COMPUTE_TILE(s_)                                                         \
    {                                                                            \
        const char* baseA = smem + (s_) * GSLOT;                                 \
        const char* baseB = smem + 2 * GSLOT + (s_) * GSLOT;                     \
        bf16x8 bfr[4][2];                                                        \
        _Pragma("unroll")                                                        \
        for (int nt = 0; nt < 4; ++nt)                                           \
            _Pragma("unroll")                                                    \
            for (int ks = 0; ks < 2; ++ks) {                                     \
                int rb = wn * 64 + nt * 16 + (lane & 15);                        \
                int c  = (ks * 32 + (lane >> 4) * 8) ^ ((rb & 7) << 3);          \
                bfr[nt][ks] = *(const bf16x8*)(baseB + rb * 128 + c * 2);        \
            }                                                                    \
        _Pragma("unroll")                                                        \
        for (int qq = 0; qq < 2; ++qq) {                                         \
            bf16x8 af[2][2];                                                     \
            _Pragma("unroll")                                                    \
            for (int mt = 0; mt < 2; ++mt)                                       \
                _Pragma("unroll")                                                \
                for (int ks = 0; ks < 2; ++ks) {                                 \
                    int ra = wm * 64 + (qq * 2 + mt) * 16 + (lane & 15);         \
                    int c  = (ks * 32 + (lane >> 4) * 8) ^ ((ra & 7) << 3);      \
                    af[mt][ks] = *(const bf16x8*)(baseA + ra * 128 + c * 2);     \
                }                                                                \
            __builtin_amdgcn_s_setprio(1);                                       \
            _Pragma("unroll")                                                    \
            for (int mt = 0; mt < 2; ++mt)                                       \
                _Pragma("unroll")                                                \
                for (int nt = 0; nt < 4; ++nt) {                                 \
                    acc[qq * 2 + mt][nt] = __builtin_amdgcn_mfma_f32_16x16x32_bf16( \
                        af[mt][0], bfr[nt][0], acc[qq * 2 + mt][nt], 0, 0, 0);   \
                    acc[qq * 2 + mt][nt] = __builtin_amdgcn_mfma_f32_16x16x32_bf16( \
                        af[mt][1], bfr[nt][1], acc[qq * 2 + mt][nt], 0, 0, 0);   \
                }                                                                \
            __builtin_amdgcn_s_setprio(0);                                       \
        }                                                                        \
    }

__global__ __launch_bounds__(256, 2) void out_gemm_128(
    const __hip_bfloat16* __restrict__ Wb,
    const __hip_bfloat16* __restrict__ gT,
    const float* __restrict__ bias,
    float* __restrict__ out)
{
    extern __shared__ char smem[];
    const int tid  = threadIdx.x;
    const int lane = tid & 63;
    const int wave = tid >> 6;
    const int wm = wave >> 1;           // 0..1 : 64 M-rows each
    const int wn = wave & 1;            // 0..1 : 64 N-rows each

    // XCD-aware swizzle: 1024 wgs, 8 XCDs, 128 per XCD (1024%8==0, bijective)
    int wg  = blockIdx.x;
    int swz = (wg & 7) * 128 + (wg >> 3);
    const int o0 = (swz & 7) * 128;     // M tile (8)
    const int n0 = (swz >> 3) * 128;    // N tile (128) over flattened (b,l)

    const int rsub = tid >> 3;                          // 0..31
    const int csw  = ((tid & 7) ^ (rsub & 7)) << 3;     // swizzled k col (elems)

    f32x4 acc[4][4] = {};

    STAGE_TILE(0, 0)
    STAGE_TILE(1, 1)

    for (int t = 0; t < 15; ++t) {
        asm volatile("s_waitcnt vmcnt(8)" ::: "memory");   // tile t landed; t+1 in flight
        __builtin_amdgcn_s_barrier();
        __builtin_amdgcn_sched_barrier(0);
        COMPUTE_TILE(t & 1)
        asm volatile("s_waitcnt lgkmcnt(0)" ::: "memory");
        __builtin_amdgcn_s_barrier();
        __builtin_amdgcn_sched_barrier(0);
        if (t < 14) STAGE_TILE(t + 2, t & 1)
    }
    asm volatile("s_waitcnt vmcnt(0)" ::: "memory");
    __builtin_amdgcn_s_barrier();
    __builtin_amdgcn_sched_barrier(0);
    COMPUTE_TILE(1)

    const int bb = n0 >> 11;
    #pragma unroll
    for (int m = 0; m < 4; ++m) {
        int o = o0 + wm * 64 + m * 16 + (lane >> 4) * 4;
        #pragma unroll
        for (int nt = 0; nt < 4; ++nt) {
            int n = n0 + wn * 64 + nt * 16 + (lane & 15);
            int l = n & 2047;
            #pragma unroll
            for (int r = 0; r < 4; ++r)
                out[((size_t)(bb * HH + o + r)) * LL + l] = acc[m][nt][r] + bias[o + r];
        }
    }
}

extern "C" void kernel_launch(void* const* d_in, const int* in_sizes, int n_in,
                              void* d_out, int out_size, void* d_ws, size_t ws_size,
                              hipStream_t stream) {
    const float* u          = (const float*)d_in[0];
    const float* log_dt     = (const float*)d_in[1];
    const float* log_w_real = (const float*)d_in[2];
    const float* w_imag     = (const float*)d_in[3];
    const float* C_re       = (const float*)d_in[4];
    const float* C_im       = (const float*)d_in[5];
    const float* Dp         = (const float*)d_in[6];
    const float* W          = (const float*)d_in[7];
    const float* bias       = (const float*)d_in[8];
    float* out = (float*)d_out;

    // d_out (64 MiB) = [AJ 16 MiB][AP 16 MiB][g 32 MiB]
    __hip_bfloat16* AJ_g = (__hip_bfloat16*)d_out;
    __hip_bfloat16* AP_g = (__hip_bfloat16*)((char*)d_out + 16777216);
    __hip_bfloat16* g    = (__hip_bfloat16*)((char*)d_out + 33554432);
    // ws: gT 33.5MB | Wb 2MB | misc 1MB
    __hip_bfloat16* gT     = (__hip_bfloat16*)d_ws;
    __hip_bfloat16* Wb     = (__hip_bfloat16*)((char*)d_ws + 33554432);
    float*          misc_g = (float*)((char*)d_ws + 35651584);

    hipFuncSetAttribute((const void*)ssm_mfma,
                        hipFuncAttributeMaxDynamicSharedMemorySize, S_TOT);
    hipFuncSetAttribute((const void*)out_gemm_128,
                        hipFuncAttributeMaxDynamicSharedMemorySize, 65536);

    aux_tables<<<dim3(HH), 256, 0, stream>>>(log_dt, log_w_real, w_imag,
                                             C_re, C_im, W, AJ_g, AP_g, misc_g, Wb);
    ssm_mfma<<<dim3(HH, 2), 512, S_TOT, stream>>>(u, AJ_g, AP_g, misc_g, Dp, g);
    transpose_g<<<dim3(HH / 64, LL / 64, BB), 256, 0, stream>>>(g, gT);
    out_gemm_128<<<dim3(1024), 256, 65536, stream>>>(Wb, gT, bias, out);
}